// Round 15
// baseline (561.961 us; speedup 1.0000x reference)
//
#include <hip/hip_runtime.h>
#include <math.h>
#include <cmath>

#define SEQ   512
#define NBATCH 64
#define BT    32768      // 64*512 tokens
#define HID   128
#define NHEAD 4
#define HD    32
#define VHD   64
#define VDIM  256
#define FFND  256

typedef __attribute__((ext_vector_type(8))) short bf16x8;
typedef __attribute__((ext_vector_type(4))) float f32x4;
typedef unsigned short u16;

__device__ __forceinline__ float gelu_f(float x){ return 0.5f*x*(1.f+erff(x*0.70710678118f)); }

__device__ __forceinline__ u16 f2bf(float f){
  union{float f; unsigned u;} v; v.f = f;
  unsigned r = v.u + 0x7FFF + ((v.u>>16)&1);
  return (u16)(r>>16);
}
__device__ __forceinline__ float bf2f(u16 u){
  union{unsigned u; float f;} v; v.u = ((unsigned)u)<<16; return v.f;
}

// async 16B global->LDS (HW scatters lane i at ldsbase + i*16)
__device__ __forceinline__ void gload16(const void* g, void* l){
  __builtin_amdgcn_global_load_lds(
      (const __attribute__((address_space(1))) unsigned*)g,
      (__attribute__((address_space(3))) unsigned*)l, 16, 0, 0);
}

// stage a 128-row x 128-u16 weight tile, XOR-swizzled (phys16 = log16 ^ (row&15))
// B-frag read: logical (row, ks*32+quad*8) -> sW[row*128 + (((ks*4+quad)^(row&15))<<3)]
#define STAGE_TILE(dst, base, strideU16, colOffU16, wid_, srow_, phys16l_)      \
  do{                                                                           \
    _Pragma("unroll")                                                           \
    for(int it_=0; it_<8; it_++){                                               \
      int blk_ = (wid_)*8 + it_;                                                \
      int row_ = blk_*4 + (srow_);                                              \
      int log16_ = (phys16l_) ^ (row_&15);                                      \
      gload16((base) + (size_t)row_*(strideU16) + (colOffU16) + log16_*8,       \
              &(dst)[blk_*512]);                                                \
    }                                                                           \
  }while(0)

// ---------------- xPos rotation table: xt[l*16+i] = (cq,sq,ck,sk) ----------------
// bit-identical to the former per-lane computation
__global__ __launch_bounds__(256) void xpos_kernel(float4* __restrict__ xt){
  int idx = blockIdx.x*256 + threadIdx.x;   // 0..8191
  int l = idx>>4, i = idx&15;
  float log2bs = log2f(((float)i + 12.8f)*(1.f/44.8f));
  float invf   = exp2f(-(float)i * (13.28771238f/16.f));
  float e  = log2bs * (float)l * (1.f/512.f);
  float scq = exp2f(e), sck = exp2f(-e);
  float ang = (float)l * invf;
  float cs = cosf(ang), sn = sinf(ang);
  xt[idx] = make_float4(cs*scq, sn*scq, cs*sck, sn*sck);
}

// ---------------- weight convert + transpose -> bf16 Wt[N][K] ----------------
// per-layer region (196608 u16): [0)qkvg 768x128  [98304)wo 128x256  [131072)f1 256x128  [163840)f2 128x256
// tail: 786432 dec_w1t 64x128 (8192); 794624 rem_w2t 64x32 (2048); 796672 rem_w3t 128x64 (8192). total 804864
__global__ __launch_bounds__(256) void wconv_kernel(
    const float* __restrict__ wq, const float* __restrict__ wk,
    const float* __restrict__ wv, const float* __restrict__ wg,
    const float* __restrict__ wo, const float* __restrict__ f1,
    const float* __restrict__ f2, const float* __restrict__ dw1,
    const float* __restrict__ w2e, const float* __restrict__ w3e,
    u16* __restrict__ Wt)
{
  int idx = blockIdx.x*256 + threadIdx.x;   // 0..804863
  if(idx >= 786432){
    int q = idx - 786432;
    if(q < 8192){ int col=q>>7, h=q&127; Wt[idx]=f2bf(dw1[h*64+col]); }
    else if(q < 10240){ int p=q-8192; int row=p>>5, col=p&31; Wt[idx]=f2bf(w2e[col*64+row]); }
    else { int p=q-10240; int row=p>>6, col=p&63; Wt[idx]=f2bf(w3e[col*128+row]); }
    return;
  }
  int layer = idx / 196608;
  int r = idx - layer*196608;
  u16* W = Wt + (size_t)layer*196608;
  const float* wq_l = wq + (size_t)layer*16384;
  const float* wk_l = wk + (size_t)layer*16384;
  const float* wv_l = wv + (size_t)layer*32768;
  const float* wg_l = wg + (size_t)layer*32768;
  const float* wo_l = wo + (size_t)layer*32768;
  const float* f1_l = f1 + (size_t)layer*32768;
  const float* f2_l = f2 + (size_t)layer*32768;
  float v;
  if(r < 98304){
    int col = r>>7, h = r&127;
    if(col<128){ int n=col>>5, d=col&31; v = wq_l[(n*128+h)*32+d]; }
    else if(col<256){ int c=col-128, n=c>>5, d=c&31; v = wk_l[(n*128+h)*32+d]; }
    else if(col<512){ int c=col-256, n=c>>6, j=c&63; v = wv_l[(n*128+h)*64+j]; }
    else { int p=col-512; v = wg_l[h*256+p]; }
    W[r] = f2bf(v);
  } else if(r < 131072){
    int q = r-98304; int col=q>>8, k=q&255;
    W[r] = f2bf(wo_l[k*128+col]);
  } else if(r < 163840){
    int q = r-131072; int col=q>>7, h=q&127;
    W[r] = f2bf(f1_l[h*256+col]);
  } else {
    int q = r-163840; int col=q>>8, k=q&255;
    W[r] = f2bf(f2_l[k*128+col]);
  }
}

// ---------------- embed (MFMA) + fused layer-0 LN1 ----------------
__global__ __launch_bounds__(256) void embed_kernel(
    const float* __restrict__ x,
    const float* __restrict__ w1, const float* __restrict__ b1,
    const float* __restrict__ b2, const float* __restrict__ b3,
    const u16* __restrict__ W23t,     // w2t[64][32] at 0, w3t[128][64] at 2048
    const float* __restrict__ lnw, const float* __restrict__ lnb,
    float* __restrict__ X, u16* __restrict__ xn)
{
  __shared__ float sx[64][6];
  __shared__ float sw1[160], sb1[32], sb2[64], sb3[128];
  __shared__ u16 big[18944];
  int t=threadIdx.x, lane=t&63, wid=t>>6, mrow=lane&15, quad=lane>>4, r0=wid*16;
  int tok0=blockIdx.x*64;

  for(int i=t;i<320;i+=256) sx[i/5][i%5]=x[(size_t)tok0*5+i];
  for(int i=t;i<160;i+=256) sw1[i]=w1[i];
  if(t<32) sb1[t]=b1[t];
  if(t<64) sb2[t]=b2[t];
  if(t<128) sb3[t]=b3[t];
  for(int c=t;c<256;c+=256){ int row=c>>2, c8=(c&3)*8;
    *(uint4*)&big[2560+row*40+c8]=*(const uint4*)&W23t[row*32+c8]; }
  for(int c=t;c<1024;c+=256){ int row=c>>3, c8=(c&7)*8;
    *(uint4*)&big[9728+row*72+c8]=*(const uint4*)&W23t[2048+row*64+c8]; }
  __syncthreads();

  for(int task=t; task<2048; task+=256){
    int tok=task>>5, j=task&31;
    float a=sb1[j];
    #pragma unroll
    for(int i=0;i<5;i++) a+=sx[tok][i]*sw1[i*32+j];
    big[tok*40+j]=f2bf(gelu_f(a));
  }
  __syncthreads();

  f32x4 h2[4];
  #pragma unroll
  for(int cc=0;cc<4;cc++) h2[cc]=(f32x4){0.f,0.f,0.f,0.f};
  {
    bf16x8 a=*(const bf16x8*)&big[(r0+mrow)*40+quad*8];
    #pragma unroll
    for(int cc=0;cc<4;cc++){
      bf16x8 b=*(const bf16x8*)&big[2560+(cc*16+mrow)*40+quad*8];
      h2[cc]=__builtin_amdgcn_mfma_f32_16x16x32_bf16(a,b,h2[cc],0,0,0);
    }
  }
  #pragma unroll
  for(int cc=0;cc<4;cc++){
    float bs=sb2[cc*16+mrow];
    #pragma unroll
    for(int reg=0;reg<4;reg++)
      big[5120+(r0+quad*4+reg)*72+cc*16+mrow]=f2bf(gelu_f(h2[cc][reg]+bs));
  }
  __syncthreads();

  f32x4 xac[8];
  #pragma unroll
  for(int cc=0;cc<8;cc++) xac[cc]=(f32x4){0.f,0.f,0.f,0.f};
  #pragma unroll
  for(int ks=0;ks<2;ks++){
    bf16x8 a=*(const bf16x8*)&big[5120+(r0+mrow)*72+ks*32+quad*8];
    #pragma unroll
    for(int cc=0;cc<8;cc++){
      bf16x8 b=*(const bf16x8*)&big[9728+(cc*16+mrow)*72+ks*32+quad*8];
      xac[cc]=__builtin_amdgcn_mfma_f32_16x16x32_bf16(a,b,xac[cc],0,0,0);
    }
  }
  __syncthreads();

  #pragma unroll
  for(int reg=0;reg<4;reg++){
    int rowl=r0+quad*4+reg, rowg=tok0+rowl;
    float xv[8], s=0.f, sq=0.f;
    #pragma unroll
    for(int cc=0;cc<8;cc++){
      float v=gelu_f(xac[cc][reg]+sb3[cc*16+mrow]);
      xv[cc]=v; s+=v; sq+=v*v;
    }
    #pragma unroll
    for(int m=1;m<16;m<<=1){ s+=__shfl_xor(s,m); sq+=__shfl_xor(sq,m); }
    float mu=s*(1.f/128.f);
    float var=sq*(1.f/128.f)-mu*mu;
    float rstd=rsqrtf(var+1e-5f);
    #pragma unroll
    for(int cc=0;cc<8;cc++){
      int col=cc*16+mrow;
      X[(size_t)rowg*128+col]=xv[cc];
      big[rowl*136+col]=f2bf((xv[cc]-mu)*rstd*lnw[col]+lnb[col]);
    }
  }
  __syncthreads();
  for(int th=t; th<1024; th+=256){
    int row=th>>4, seg=th&15;
    *(uint4*)&xn[(size_t)(tok0+row)*128+seg*8]=*(const uint4*)&big[row*136+seg*8];
  }
}

// ---------------- qkvg epilogue helper (shared by qkvg_kernel and mlpq tail) ----------------
__device__ __forceinline__ void qkvg_epilogue(
    int nc, f32x4 acc[2][4], u16* stg, const float4* __restrict__ xt,
    int t, int mrow, int quad, int r0q, int c0q, int b, int l0, int tok0,
    u16* __restrict__ Q, u16* __restrict__ K,
    u16* __restrict__ Vt, u16* __restrict__ G)
{
  if(nc < 2){
    bool isK = (nc==1);
    #pragma unroll
    for(int cc=0;cc<4;cc++){
      int colc = c0q + cc*16 + mrow;
      int i = (colc&31)>>1;
      #pragma unroll
      for(int rr=0;rr<2;rr++){
        #pragma unroll
        for(int reg=0;reg<4;reg++){
          int rowl = r0q + rr*16 + quad*4 + reg;
          int l = l0 + rowl;
          float v = acc[rr][cc][reg];
          float partner = __shfl_xor(v, 1);
          float4 T = xt[l*16 + i];
          float cs = isK ? T.z : T.x;
          float sn = isK ? T.w : T.y;
          float o = (colc&1) ? (v*cs + partner*sn) : (v*cs - partner*sn);
          stg[rowl*136 + colc] = f2bf(o);
        }
      }
    }
    __syncthreads();
    u16* O = isK ? K : Q;
    for(int th=t; th<1024; th+=256){
      int row=th>>4, n=(th>>2)&3, seg=th&3;
      *(uint4*)&O[(((size_t)(b*4+n)*512) + (l0+row))*32 + seg*8]
        = *(const uint4*)&stg[row*136 + n*32 + seg*8];
    }
  } else if(nc < 4){
    #pragma unroll
    for(int cc=0;cc<4;cc++){
      int colc = c0q + cc*16 + mrow;
      #pragma unroll
      for(int rr=0;rr<2;rr++){
        #pragma unroll
        for(int reg=0;reg<4;reg++){
          int rowl = r0q + rr*16 + quad*4 + reg;
          stg[colc*72 + rowl] = f2bf(acc[rr][cc][reg]);
        }
      }
    }
    __syncthreads();
    int jbase = (nc-2)*128;
    for(int th=t; th<1024; th+=256){
      int row=th>>3, seg=th&7;
      int jg = jbase + row; int n = jg>>6, j = jg&63;
      *(uint4*)&Vt[(((size_t)(b*4+n)*64) + j)*512 + l0 + seg*8]
        = *(const uint4*)&stg[row*72 + seg*8];
    }
  } else {
    #pragma unroll
    for(int cc=0;cc<4;cc++){
      int colc = c0q + cc*16 + mrow;
      #pragma unroll
      for(int rr=0;rr<2;rr++){
        #pragma unroll
        for(int reg=0;reg<4;reg++){
          int rowl = r0q + rr*16 + quad*4 + reg;
          stg[rowl*136 + colc] = f2bf(acc[rr][cc][reg]);
        }
      }
    }
    __syncthreads();
    int gc0 = (nc-4)*128;
    for(int th=t; th<1024; th+=256){
      int row=th>>4, seg=th&15;
      *(uint4*)&G[((size_t)(tok0+row))*256 + gc0 + seg*8]
        = *(const uint4*)&stg[row*136 + seg*8];
    }
  }
}

// ---------------- qkvg v3 (layer 0 only): async swizzled weight staging ----------------
__global__ __launch_bounds__(256) void qkvg_kernel(
    const u16* __restrict__ A, const u16* __restrict__ Wt,
    const float4* __restrict__ xt,
    u16* __restrict__ Q, u16* __restrict__ K,
    u16* __restrict__ Vt, u16* __restrict__ G)
{
  __shared__ u16 sW[128*128];      // 32 KB swizzled weights; reused as epilogue staging
  u16* stg = sW;
  int t = threadIdx.x, lane = t&63, wid = t>>6;
  int mrow = lane&15, quad = lane>>4;
  int srow = lane>>4, phys16l = lane&15;
  int r0q = (wid>>1)*32, c0q = (wid&1)*64;
  int tok0 = blockIdx.x*64;
  int b = tok0>>9, l0 = tok0&511;

  bf16x8 a0f[4], a1f[4];
  #pragma unroll
  for(int ks=0; ks<4; ks++){
    a0f[ks] = *(const bf16x8*)&A[(size_t)(tok0+r0q+mrow)*128 + ks*32+quad*8];
    a1f[ks] = *(const bf16x8*)&A[(size_t)(tok0+r0q+16+mrow)*128 + ks*32+quad*8];
  }

  for(int ch=0; ch<3; ch++){
    int nc = blockIdx.y*3 + ch;   // 0..5
    if(ch) __syncthreads();
    STAGE_TILE(sW, Wt + (size_t)nc*16384, 128, 0, wid, srow, phys16l);
    __syncthreads();

    f32x4 acc[2][4];
    #pragma unroll
    for(int rr=0;rr<2;rr++)
      #pragma unroll
      for(int cc=0;cc<4;cc++) acc[rr][cc] = (f32x4){0.f,0.f,0.f,0.f};
    #pragma unroll
    for(int ks=0; ks<4; ks++){
      #pragma unroll
      for(int cc=0; cc<4; cc++){
        bf16x8 bb = *(const bf16x8*)&sW[(c0q+cc*16+mrow)*128 + (((ks*4+quad)^mrow)<<3)];
        acc[0][cc] = __builtin_amdgcn_mfma_f32_16x16x32_bf16(a0f[ks],bb,acc[0][cc],0,0,0);
        acc[1][cc] = __builtin_amdgcn_mfma_f32_16x16x32_bf16(a1f[ks],bb,acc[1][cc],0,0,0);
      }
    }
    __syncthreads();
    qkvg_epilogue(nc, acc, stg, xt, t, mrow, quad, r0q, c0q, b, l0, tok0, Q, K, Vt, G);
  }
}

// ---------------- fused MLP + qkvg(next layer): xn never touches HBM ----------------
__global__ __launch_bounds__(256) void mlpq_kernel(
    const u16* __restrict__ Gated, const u16* __restrict__ Wo,
    const u16* __restrict__ W1t, const float* __restrict__ b1,
    const u16* __restrict__ W2t, const float* __restrict__ b2,
    const float* __restrict__ Xin,
    const float* __restrict__ ln2w, const float* __restrict__ ln2b,
    const float* __restrict__ ln1w, const float* __restrict__ ln1b,
    float* __restrict__ Xout,
    const u16* __restrict__ Wq,   // next layer qkvg weights (nullptr on last layer)
    const float4* __restrict__ xt,
    u16* __restrict__ Q, u16* __restrict__ K,
    u16* __restrict__ Vt, u16* __restrict__ G)
{
  __shared__ u16 sW[128*128];   // 32768 B: swizzled weights / fp32 X staging / qkvg epilogue stg
  __shared__ u16 sT[64*136];    // 17408 B: Z / H / xn (kept in LDS)
  int t=threadIdx.x, lane=t&63, wid=t>>6, mrow=lane&15, quad=lane>>4, r0=wid*16;
  int tok0=blockIdx.x*64;
  int srow = lane>>4, phys16l = lane&15;

  // gfrag direct from global (own rows)
  bf16x8 gfrag[8];
  #pragma unroll
  for(int ks=0;ks<8;ks++)
    gfrag[ks]=*(const bf16x8*)&Gated[(size_t)(tok0+r0+mrow)*256 + ks*32+quad*8];

  // ---- wo: K=256 in 2 halves (full N=128 resident)
  f32x4 yac[8];
  #pragma unroll
  for(int ch=0;ch<8;ch++) yac[ch]=(f32x4){0.f,0.f,0.f,0.f};
  STAGE_TILE(sW, Wo, 256, 0, wid, srow, phys16l);
  __syncthreads();
  #pragma unroll
  for(int kh=0; kh<2; kh++){
    #pragma unroll
    for(int ch=0;ch<8;ch++){
      #pragma unroll
      for(int ks=0;ks<4;ks++){
        bf16x8 b=*(const bf16x8*)&sW[(ch*16+mrow)*128 + (((ks*4+quad)^mrow)<<3)];
        yac[ch]=__builtin_amdgcn_mfma_f32_16x16x32_bf16(gfrag[kh*4+ks],b,yac[ch],0,0,0);
      }
    }
    if(kh==0){
      __syncthreads();
      STAGE_TILE(sW, Wo, 256, 128, wid, srow, phys16l);
      __syncthreads();
    }
  }

  // ---- Y = yac + Xin (regs); LN2 -> Z bf16 into sT (own rows)
  float yv[8][4];
  #pragma unroll
  for(int reg=0;reg<4;reg++){
    int rowl=r0+quad*4+reg, rowg=tok0+rowl;
    float s=0.f, sq=0.f;
    #pragma unroll
    for(int ch=0;ch<8;ch++){
      float v=yac[ch][reg]+Xin[(size_t)rowg*128+ch*16+mrow];
      yv[ch][reg]=v; s+=v; sq+=v*v;
    }
    #pragma unroll
    for(int m=1;m<16;m<<=1){ s+=__shfl_xor(s,m); sq+=__shfl_xor(sq,m); }
    float mu=s*(1.f/128.f);
    float var=sq*(1.f/128.f)-mu*mu;
    float rstd=rsqrtf(var+1e-5f);
    #pragma unroll
    for(int ch=0;ch<8;ch++){
      int col=ch*16+mrow;
      sT[rowl*136+col]=f2bf((yv[ch][reg]-mu)*rstd*ln2w[col]+ln2b[col]);
    }
  }
  bf16x8 az[4];
  #pragma unroll
  for(int ks=0;ks<4;ks++) az[ks]=*(const bf16x8*)&sT[(r0+mrow)*136+ks*32+quad*8];
  __syncthreads();

  // ---- ffn1: N=256 in 2 halves of 128 cols (full K=128 resident); H-half -> sT
  bf16x8 hfrag[8];
  #pragma unroll
  for(int nh=0; nh<2; nh++){
    STAGE_TILE(sW, W1t + (size_t)nh*16384, 128, 0, wid, srow, phys16l);
    __syncthreads();
    f32x4 hac[8];
    #pragma unroll
    for(int ch=0;ch<8;ch++) hac[ch]=(f32x4){0.f,0.f,0.f,0.f};
    #pragma unroll
    for(int ch=0;ch<8;ch++){
      #pragma unroll
      for(int ks=0;ks<4;ks++){
        bf16x8 b=*(const bf16x8*)&sW[(ch*16+mrow)*128 + (((ks*4+quad)^mrow)<<3)];
        hac[ch]=__builtin_amdgcn_mfma_f32_16x16x32_bf16(az[ks],b,hac[ch],0,0,0);
      }
    }
    #pragma unroll
    for(int ch=0;ch<8;ch++){
      float bs=b1[nh*128+ch*16+mrow];
      #pragma unroll
      for(int reg=0;reg<4;reg++)
        sT[(r0+quad*4+reg)*136 + ch*16+mrow]=f2bf(gelu_f(hac[ch][reg]+bs));
    }
    #pragma unroll
    for(int ks=0;ks<4;ks++) hfrag[nh*4+ks]=*(const bf16x8*)&sT[(r0+mrow)*136+ks*32+quad*8];
    __syncthreads();
  }

  // ---- ffn2: K=256 in 2 halves (full N=128 resident)
  f32x4 xac[8];
  #pragma unroll
  for(int ch=0;ch<8;ch++) xac[ch]=(f32x4){0.f,0.f,0.f,0.f};
  STAGE_TILE(sW, W2t, 256, 0, wid, srow, phys16l);
  __syncthreads();
  #pragma unroll
  for(int kh=0; kh<2; kh++){
    #pragma unroll
    for(int ch=0;ch<8;ch++){
      #pragma unroll
      for(int ks=0;ks<4;ks++){
        bf16x8 b=*(const bf16x8*)&sW[(ch*16+mrow)*128 + (((ks*4+quad)^mrow)<<3)];
        xac[ch]=__builtin_amdgcn_mfma_f32_16x16x32_bf16(hfrag[kh*4+ks],b,xac[ch],0,0,0);
      }
    }
    __syncthreads();
    if(kh==0){
      STAGE_TILE(sW, W2t, 256, 128, wid, srow, phys16l);
      __syncthreads();
    }
  }

  // ---- epilogue: X = xac + b2 + Y; LN1(next) -> sT (xn, LDS-resident)
  float* fst = (float*)sW;       // [64][128] = 32768 B
  #pragma unroll
  for(int reg=0;reg<4;reg++){
    int rowl=r0+quad*4+reg;
    float xv[8], s=0.f, sq=0.f;
    #pragma unroll
    for(int ch=0;ch<8;ch++){
      float v=xac[ch][reg]+b2[ch*16+mrow]+yv[ch][reg];
      xv[ch]=v; s+=v; sq+=v*v;
    }
    #pragma unroll
    for(int m=1;m<16;m<<=1){ s+=__shfl_xor(s,m); sq+=__shfl_xor(sq,m); }
    float mu=s*(1.f/128.f);
    float var=sq*(1.f/128.f)-mu*mu;
    float rstd=rsqrtf(var+1e-5f);
    #pragma unroll
    for(int ch=0;ch<8;ch++){
      int col=ch*16+mrow;
      fst[rowl*128+col]=xv[ch];
      sT[rowl*136+col]=f2bf((xv[ch]-mu)*rstd*ln1w[col]+ln1b[col]);
    }
  }
  __syncthreads();
  for(int th=t; th<2048; th+=256){
    int row=th>>5, c4=(th&31)*4;
    *(float4*)&Xout[(size_t)(tok0+row)*128+c4]=*(const float4*)&fst[row*128+c4];
  }

  if(!Wq) return;

  // ---- fused qkvg for next layer: A-frags from sT (xn in LDS)
  int r0q = (wid>>1)*32, c0q = (wid&1)*64;
  int b = tok0>>9, l0 = tok0&511;
  bf16x8 a0f[4], a1f[4];
  #pragma unroll
  for(int ks=0; ks<4; ks++){
    a0f[ks] = *(const bf16x8*)&sT[(r0q+mrow)*136 + ks*32+quad*8];
    a1f[ks] = *(const bf16x8*)&sT[(r0q+16+mrow)*136 + ks*32+quad*8];
  }
  __syncthreads();   // Xout reads of fst(sW) done before STAGE overwrites

  for(int nc=0; nc<6; nc++){
    if(nc) __syncthreads();   // prev epilogue's stg reads done
    STAGE_TILE(sW, Wq + (size_t)nc*16384, 128, 0, wid, srow, phys16l);
    __syncthreads();

    f32x4 acc[2][4];
    #pragma unroll
    for(int rr=0;rr<2;rr++)
      #pragma unroll
      for(int cc=0;cc<4;cc++) acc[rr][cc] = (f32x4){0.f,0.f,0.f,0.f};
    #pragma unroll
    for(int ks=0; ks<4; ks++){
      #pragma unroll
      for(int cc=0; cc<4; cc++){
        bf16x8 bb = *(const bf16x8*)&sW[(c0q+cc*16+mrow)*128 + (((ks*4+quad)^mrow)<<3)];
        acc[0][cc] = __builtin_amdgcn_mfma_f32_16x16x32_bf16(a0f[ks],bb,acc[0][cc],0,0,0);
        acc[1][cc] = __builtin_amdgcn_mfma_f32_16x16x32_bf16(a1f[ks],bb,acc[1][cc],0,0,0);
      }
    }
    __syncthreads();
    qkvg_epilogue(nc, acc, sW, xt, t, mrow, quad, r0q, c0q, b, l0, tok0, Q, K, Vt, G);
  }
}

// ---------------- retention v3: double-buffered K/Vt prefetch + groupnorm + silu gate ----------------
__global__ __launch_bounds__(256) void retmfma_kernel(
    const u16* __restrict__ Q, const u16* __restrict__ K,
    const u16* __restrict__ Vt, const u16* __restrict__ G,
    const float* __restrict__ gnw, const float* __restrict__ gnb,
    u16* __restrict__ Gated, float4 log2g)
{
  int idx = blockIdx.x;
  int bn = ((idx>>6)<<3) | (idx&7);
  int lt = (idx>>3)&7;
  int n = bn & 3, b = bn >> 2;
  float lg2g = (n==0)?log2g.x:(n==1)?log2g.y:(n==2)?log2g.z:log2g.w;
  __shared__ u16 sK[2][64][40];
  __shared__ u16 sVt[2][64][72];
  __shared__ u16 sS[64][72];
  int t = threadIdx.x, lane = t&63, wid = t>>6;
  int mrow = lane&15, quad = lane>>4;
  int r0 = wid*16;

  bf16x8 qa = *(const bf16x8*)&Q[((size_t)bn*512 + lt*64 + r0+mrow)*32 + quad*8];

  f32x4 oacc[4];
  #pragma unroll
  for(int cc=0;cc<4;cc++) oacc[cc] = (f32x4){0.f,0.f,0.f,0.f};
  float gp1 = exp2f(lg2g), gp2 = gp1*gp1, gp3 = gp2*gp1;
  float gpow[4] = {1.f, gp1, gp2, gp3};
  float gw[4], gb[4];
  #pragma unroll
  for(int cc=0;cc<4;cc++){ gw[cc]=gnw[n*64+cc*16+mrow]; gb[cc]=gnb[n*64+cc*16+mrow]; }
  int rowl0 = lt*64 + r0 + quad*4;

  int krow = t>>2, kc8 = (t&3)*8;
  int vrow = t>>3, vc8 = (t&7)*8;

  {
    *(uint4*)&sK[0][krow][kc8] = *(const uint4*)&K[((size_t)bn*512 + krow)*32 + kc8];
    *(uint4*)&sVt[0][vrow][vc8]    = *(const uint4*)&Vt[((size_t)bn*64 + vrow)*512    + vc8];
    *(uint4*)&sVt[0][vrow+32][vc8] = *(const uint4*)&Vt[((size_t)bn*64 + vrow+32)*512 + vc8];
  }
  __syncthreads();

  for(int mt=0; mt<=lt; mt++){
    int cur = mt&1;
    if(mt<lt){
      int nx = cur^1, m1 = mt+1;
      *(uint4*)&sK[nx][krow][kc8] = *(const uint4*)&K[((size_t)bn*512 + m1*64 + krow)*32 + kc8];
      *(uint4*)&sVt[nx][vrow][vc8]    = *(const uint4*)&Vt[((size_t)bn*64 + vrow)*512    + m1*64 + vc8];
      *(uint4*)&sVt[nx][vrow+32][vc8] = *(const uint4*)&Vt[((size_t)bn*64 + vrow+32)*512 + m1*64 + vc8];
    }
    f32x4 sacc[4];
    #pragma unroll
    for(int cc=0;cc<4;cc++){
      bf16x8 bb = *(const bf16x8*)&sK[cur][cc*16+mrow][quad*8];
      sacc[cc] = __builtin_amdgcn_mfma_f32_16x16x32_bf16(qa,bb,(f32x4){0.f,0.f,0.f,0.f},0,0,0);
    }
    #pragma unroll
    for(int cc=0;cc<4;cc++){
      int colm = mt*64 + cc*16 + mrow;
      int d0 = rowl0 - colm;
      float w0 = exp2f(lg2g*(float)d0);
      #pragma unroll
      for(int reg=0;reg<4;reg++){
        float w = (d0+reg>=0) ? w0*gpow[reg] : 0.f;
        sS[r0+quad*4+reg][cc*16+mrow] = f2bf(sacc[cc][reg]*w);
      }
    }
    __syncthreads();
    #pragma unroll
    for(int ks=0;ks<2;ks++){
      bf16x8 a = *(const bf16x8*)&sS[r0+mrow][ks*32+quad*8];
      #pragma unroll
      for(int cc=0;cc<4;cc++){
        bf16x8 bb = *(const bf16x8*)&sVt[cur][cc*16+mrow][ks*32+quad*8];
        oacc[cc] = __builtin_amdgcn_mfma_f32_16x16x32_bf16(a,bb,oacc[cc],0,0,0);
      }
    }
    __syncthreads();
  }

  #pragma unroll
  for(int reg=0;reg<4;reg++){
    float s=0.f, sq=0.f;
    #pragma unroll
    for(int cc=0;cc<4;cc++){ float v=oacc[cc][reg]; s+=v; sq+=v*v; }
    #pragma unroll
    for(int m=1;m<16;m<<=1){ s+=__shfl_xor(s,m); sq+=__shfl_xor(sq,m); }
    float mu = s*(1.f/64.f);
    float var = sq*(1.f/64.f) - mu*mu;
    float rn = rsqrtf(var + 1e-5f);
    int rowl = r0 + quad*4 + reg;
    int l = lt*64 + rowl;
    size_t gbase = ((size_t)(b*512 + l))*256 + n*64;
    #pragma unroll
    for(int cc=0;cc<4;cc++){
      float gg = bf2f(G[gbase + cc*16+mrow]);
      float gate = gg/(1.f+expf(-gg));
      sS[rowl][cc*16+mrow] = f2bf(gate*((oacc[cc][reg]-mu)*rn*gw[cc] + gb[cc]));
    }
  }
  __syncthreads();
  for(int th=t; th<512; th+=256){
    int row=th>>3, seg=th&7;
    *(uint4*)&Gated[((size_t)(b*512 + lt*64 + row))*256 + n*64 + seg*8]
      = *(const uint4*)&sS[row][seg*8];
  }
}

// ---------------- decoder (MFMA): softmax(gelu(X@w1+b1)@w2+b2) ----------------
__global__ __launch_bounds__(256) void dec_kernel(
    const float* __restrict__ X, const u16* __restrict__ W1t,
    const float* __restrict__ b1, const float* __restrict__ w2,
    const float* __restrict__ b2, float* __restrict__ out)
{
  __shared__ u16 sA[64][136];
  __shared__ u16 sW[64][136];
  __shared__ float sH[64][68];
  __shared__ float sL[64*20];
  __shared__ float sw2[64*20];
  __shared__ float sb2[20];
  int t = threadIdx.x, lane = t&63, wid = t>>6;
  int mrow = lane&15, quad = lane>>4;
  int tok0 = blockIdx.x*64;

  for(int th=t; th<2048; th+=256){
    int row=th>>5, c4=(th&31)*4;
    float4 v = *(const float4*)&X[(size_t)(tok0+row)*128 + c4];
    ushort4 p; p.x=f2bf(v.x); p.y=f2bf(v.y); p.z=f2bf(v.z); p.w=f2bf(v.w);
    *(ushort4*)&sA[row][c4] = p;
  }
  for(int th=t; th<1024; th+=256){
    int row=th>>4, c8=(th&15)*8;
    *(uint4*)&sW[row][c8] = *(const uint4*)&W1t[(size_t)row*128 + c8];
  }
  for(int i=t;i<1280;i+=256) sw2[i]=w2[i];
  if(t<20) sb2[t]=b2[t];
  __syncthreads();

  int r0 = wid*16;
  f32x4 acc[4];
  #pragma unroll
  for(int cc=0;cc<4;cc++) acc[cc] = (f32x4){0.f,0.f,0.f,0.f};
  #pragma unroll
  for(int ks=0; ks<4; ks++){
    int koff = ks*32 + quad*8;
    bf16x8 a = *(const bf16x8*)&sA[r0+mrow][koff];
    #pragma unroll
    for(int cc=0; cc<4; cc++){
      bf16x8 b = *(const bf16x8*)&sW[cc*16+mrow][koff];
      acc[cc] = __builtin_amdgcn_mfma_f32_16x16x32_bf16(a,b,acc[cc],0,0,0);
    }
  }
  #pragma unroll
  for(int cc=0;cc<4;cc++){
    int col = cc*16 + mrow;
    float bb = b1[col];
    #pragma unroll
    for(int reg=0;reg<4;reg++){
      sH[r0 + quad*4 + reg][col] = gelu_f(acc[cc][reg] + bb);
    }
  }
  __syncthreads();

  for(int task=t; task<1280; task+=256){
    int tk = task/20, o = task - tk*20;
    float a = sb2[o];
    for(int k=0;k<64;k++) a += sH[tk][k]*sw2[k*20+o];
    sL[tk*20+o] = a;
  }
  __syncthreads();
  if(t < 64){
    float mx = -1e30f;
    #pragma unroll
    for(int o=0;o<20;o++) mx = fmaxf(mx, sL[t*20+o]);
    float sum = 0.f;
    float e[20];
    #pragma unroll
    for(int o=0;o<20;o++){ e[o]=expf(sL[t*20+o]-mx); sum += e[o]; }
    float inv = 1.f/sum;
    #pragma unroll
    for(int o=0;o<20;o++) sL[t*20+o] = e[o]*inv;
  }
  __syncthreads();
  for(int th=t; th<1280; th+=256){
    out[(size_t)tok0*20 + th] = sL[th];
  }
}

extern "C" void kernel_launch(void* const* d_in, const int* in_sizes, int n_in,
                              void* d_out, int out_size, void* d_ws, size_t ws_size,
                              hipStream_t stream) {
  (void)in_sizes; (void)n_in; (void)out_size; (void)ws_size;
  const float* x      = (const float*)d_in[0];
  const float* rem_w1 = (const float*)d_in[1];
  const float* rem_b1 = (const float*)d_in[2];
  const float* rem_w2 = (const float*)d_in[3];
  const float* rem_b2 = (const float*)d_in[4];
  const float* rem_w3 = (const float*)d_in[5];
  const float* rem_b3 = (const float*)d_in[6];
  const float* wq     = (const float*)d_in[7];
  const float* wk     = (const float*)d_in[8];
  const float* wv     = (const float*)d_in[9];
  const float* wg     = (const float*)d_in[10];
  const float* wo     = (const float*)d_in[11];
  const float* gn_w   = (const float*)d_in[12];
  const float* gn_b   = (const float*)d_in[13];
  const float* ln1_w  = (const float*)d_in[14];
  const float* ln1_b  = (const float*)d_in[15];
  const float* ln2_w  = (const float*)d_in[16];
  const float* ln2_b  = (const float*)d_in[17];
  const float* ffn_w1 = (const float*)d_in[18];
  const float* ffn_b1 = (const float*)d_in[19];
  const float* ffn_w2 = (const float*)d_in[20];
  const float* ffn_b2 = (const float*)d_in[21];
  const float* dec_w1 = (const float*)d_in[22];
  const float* dec_b1 = (const float*)d_in[23];
  const float* dec_w2 = (const float*)d_in[24];
  const float* dec_b2 = (const float*)d_in[25];
  float* outp = (float*)d_out;

  const size_t S128 = (size_t)BT*128;
  const size_t S256 = (size_t)BT*256;
  float* ws = (float*)d_ws;
  float* Xb = ws;                  // residual X        (S128 f32)
  u16*  Qb16    = (u16*)(Xb + S128);     // Q bf16 head-layout (BT*32)
  u16*  Kb16    = Qb16 + (size_t)BT*32;
  u16*  Vt16    = Kb16 + (size_t)BT*32;  // V bf16 transposed (BT*64)
  u16*  XnBf    = Vt16 + (size_t)BT*64;  // LN out bf16 (layer-0 only)
  u16*  GBf     = XnBf + S128;           // G bf16        (S256)
  u16*  GatedBf = GBf + S256;            // gated        (S256)
  u16*  WtBf    = GatedBf + S256;        // bf16 weights  (804864 u16)
  float4* XposT = (float4*)(WtBf + 804864); // xPos table (8192 float4 = 128 KB)

  double lgA = log(1.0/32.0), lgB = log(1.0/512.0);
  float4 l2g;
  {
    double g0 = 1.0 - exp(lgA + 0.0*(lgB-lgA)/3.0);
    double g1 = 1.0 - exp(lgA + 1.0*(lgB-lgA)/3.0);
    double g2 = 1.0 - exp(lgA + 2.0*(lgB-lgA)/3.0);
    double g3 = 1.0 - exp(lgA + 3.0*(lgB-lgA)/3.0);
    l2g.x = (float)(log(g0)/log(2.0));
    l2g.y = (float)(log(g1)/log(2.0));
    l2g.z = (float)(log(g2)/log(2.0));
    l2g.w = (float)(log(g3)/log(2.0));
  }

  xpos_kernel<<<32, 256, 0, stream>>>(XposT);
  wconv_kernel<<<3144, 256, 0, stream>>>(wq, wk, wv, wg, wo, ffn_w1, ffn_w2, dec_w1,
                                         rem_w2, rem_w3, WtBf);
  embed_kernel<<<BT/64, 256, 0, stream>>>(x, rem_w1, rem_b1, rem_b2, rem_b3,
                                          WtBf+794624, ln1_w, ln1_b, Xb, XnBf);
  qkvg_kernel<<<dim3(BT/64,2), 256, 0, stream>>>(XnBf, WtBf, XposT, Qb16, Kb16, Vt16, GBf);

  for(int li=0; li<4; li++){
    u16* Wt_l = WtBf + (size_t)li*196608;
    const float* gnw_l = gn_w + (size_t)li*VDIM;
    const float* gnb_l = gn_b + (size_t)li*VDIM;
    const float* l2w = ln2_w + (size_t)li*HID, *l2b = ln2_b + (size_t)li*HID;
    const float* f1b = ffn_b1 + (size_t)li*FFND;
    const float* f2b = ffn_b2 + (size_t)li*HID;
    int nli = (li+1)&3;
    const float* n1w = ln1_w + (size_t)nli*HID, *n1b = ln1_b + (size_t)nli*HID;
    const u16* Wq_next = (li<3) ? (WtBf + (size_t)(li+1)*196608) : nullptr;

    retmfma_kernel<<<2048, 256, 0, stream>>>(Qb16, Kb16, Vt16, GBf, gnw_l, gnb_l, GatedBf, l2g);
    mlpq_kernel<<<BT/64, 256, 0, stream>>>(
        GatedBf, Wt_l+98304, Wt_l+131072, f1b, Wt_l+163840, f2b,
        Xb, l2w, l2b, n1w, n1b, Xb,
        Wq_next, XposT, Qb16, Kb16, Vt16, GBf);
  }

  dec_kernel<<<BT/64, 256, 0, stream>>>(Xb, WtBf+786432, dec_b1, dec_w2, dec_b2, outp);
}

// Round 16
// 455.404 us; speedup vs baseline: 1.2340x; 1.2340x over previous
//
#include <hip/hip_runtime.h>
#include <math.h>
#include <cmath>

#define SEQ   512
#define NBATCH 64
#define BT    32768      // 64*512 tokens
#define HID   128
#define NHEAD 4
#define HD    32
#define VHD   64
#define VDIM  256
#define FFND  256

typedef __attribute__((ext_vector_type(8))) short bf16x8;
typedef __attribute__((ext_vector_type(4))) float f32x4;
typedef unsigned short u16;

__device__ __forceinline__ float gelu_f(float x){ return 0.5f*x*(1.f+erff(x*0.70710678118f)); }

__device__ __forceinline__ u16 f2bf(float f){
  union{float f; unsigned u;} v; v.f = f;
  unsigned r = v.u + 0x7FFF + ((v.u>>16)&1);
  return (u16)(r>>16);
}
__device__ __forceinline__ float bf2f(u16 u){
  union{unsigned u; float f;} v; v.u = ((unsigned)u)<<16; return v.f;
}

// async 16B global->LDS (HW scatters lane i at ldsbase + i*16)
__device__ __forceinline__ void gload16(const void* g, void* l){
  __builtin_amdgcn_global_load_lds(
      (const __attribute__((address_space(1))) unsigned*)g,
      (__attribute__((address_space(3))) unsigned*)l, 16, 0, 0);
}

// stage a 128-row x 128-u16 weight tile, XOR-swizzled (phys16 = log16 ^ (row&15))
// B-frag read: logical (row, ks*32+quad*8) -> sW[row*128 + (((ks*4+quad)^(row&15))<<3)]
#define STAGE_TILE(dst, base, strideU16, colOffU16, wid_, srow_, phys16l_)      \
  do{                                                                           \
    _Pragma("unroll")                                                           \
    for(int it_=0; it_<8; it_++){                                               \
      int blk_ = (wid_)*8 + it_;                                                \
      int row_ = blk_*4 + (srow_);                                              \
      int log16_ = (phys16l_) ^ (row_&15);                                      \
      gload16((base) + (size_t)row_*(strideU16) + (colOffU16) + log16_*8,       \
              &(dst)[blk_*512]);                                                \
    }                                                                           \
  }while(0)

// ---------------- weight convert + transpose -> bf16 Wt[N][K] ----------------
// per-layer region (196608 u16): [0)qkvg 768x128  [98304)wo 128x256  [131072)f1 256x128  [163840)f2 128x256
// tail: 786432 dec_w1t 64x128 (8192); 794624 rem_w2t 64x32 (2048); 796672 rem_w3t 128x64 (8192). total 804864
__global__ __launch_bounds__(256) void wconv_kernel(
    const float* __restrict__ wq, const float* __restrict__ wk,
    const float* __restrict__ wv, const float* __restrict__ wg,
    const float* __restrict__ wo, const float* __restrict__ f1,
    const float* __restrict__ f2, const float* __restrict__ dw1,
    const float* __restrict__ w2e, const float* __restrict__ w3e,
    u16* __restrict__ Wt)
{
  int idx = blockIdx.x*256 + threadIdx.x;   // 0..804863
  if(idx >= 786432){
    int q = idx - 786432;
    if(q < 8192){ int col=q>>7, h=q&127; Wt[idx]=f2bf(dw1[h*64+col]); }
    else if(q < 10240){ int p=q-8192; int row=p>>5, col=p&31; Wt[idx]=f2bf(w2e[col*64+row]); }
    else { int p=q-10240; int row=p>>6, col=p&63; Wt[idx]=f2bf(w3e[col*128+row]); }
    return;
  }
  int layer = idx / 196608;
  int r = idx - layer*196608;
  u16* W = Wt + (size_t)layer*196608;
  const float* wq_l = wq + (size_t)layer*16384;
  const float* wk_l = wk + (size_t)layer*16384;
  const float* wv_l = wv + (size_t)layer*32768;
  const float* wg_l = wg + (size_t)layer*32768;
  const float* wo_l = wo + (size_t)layer*32768;
  const float* f1_l = f1 + (size_t)layer*32768;
  const float* f2_l = f2 + (size_t)layer*32768;
  float v;
  if(r < 98304){
    int col = r>>7, h = r&127;
    if(col<128){ int n=col>>5, d=col&31; v = wq_l[(n*128+h)*32+d]; }
    else if(col<256){ int c=col-128, n=c>>5, d=c&31; v = wk_l[(n*128+h)*32+d]; }
    else if(col<512){ int c=col-256, n=c>>6, j=c&63; v = wv_l[(n*128+h)*64+j]; }
    else { int p=col-512; v = wg_l[h*256+p]; }
    W[r] = f2bf(v);
  } else if(r < 131072){
    int q = r-98304; int col=q>>8, k=q&255;
    W[r] = f2bf(wo_l[k*128+col]);
  } else if(r < 163840){
    int q = r-131072; int col=q>>7, h=q&127;
    W[r] = f2bf(f1_l[h*256+col]);
  } else {
    int q = r-163840; int col=q>>8, k=q&255;
    W[r] = f2bf(f2_l[k*128+col]);
  }
}

// ---------------- embed (MFMA) + fused layer-0 LN1 ----------------
__global__ __launch_bounds__(256) void embed_kernel(
    const float* __restrict__ x,
    const float* __restrict__ w1, const float* __restrict__ b1,
    const float* __restrict__ b2, const float* __restrict__ b3,
    const u16* __restrict__ W23t,     // w2t[64][32] at 0, w3t[128][64] at 2048
    const float* __restrict__ lnw, const float* __restrict__ lnb,
    float* __restrict__ X, u16* __restrict__ xn)
{
  __shared__ float sx[64][6];
  __shared__ float sw1[160], sb1[32], sb2[64], sb3[128];
  __shared__ u16 big[18944];
  int t=threadIdx.x, lane=t&63, wid=t>>6, mrow=lane&15, quad=lane>>4, r0=wid*16;
  int tok0=blockIdx.x*64;

  for(int i=t;i<320;i+=256) sx[i/5][i%5]=x[(size_t)tok0*5+i];
  for(int i=t;i<160;i+=256) sw1[i]=w1[i];
  if(t<32) sb1[t]=b1[t];
  if(t<64) sb2[t]=b2[t];
  if(t<128) sb3[t]=b3[t];
  for(int c=t;c<256;c+=256){ int row=c>>2, c8=(c&3)*8;
    *(uint4*)&big[2560+row*40+c8]=*(const uint4*)&W23t[row*32+c8]; }
  for(int c=t;c<1024;c+=256){ int row=c>>3, c8=(c&7)*8;
    *(uint4*)&big[9728+row*72+c8]=*(const uint4*)&W23t[2048+row*64+c8]; }
  __syncthreads();

  for(int task=t; task<2048; task+=256){
    int tok=task>>5, j=task&31;
    float a=sb1[j];
    #pragma unroll
    for(int i=0;i<5;i++) a+=sx[tok][i]*sw1[i*32+j];
    big[tok*40+j]=f2bf(gelu_f(a));
  }
  __syncthreads();

  f32x4 h2[4];
  #pragma unroll
  for(int cc=0;cc<4;cc++) h2[cc]=(f32x4){0.f,0.f,0.f,0.f};
  {
    bf16x8 a=*(const bf16x8*)&big[(r0+mrow)*40+quad*8];
    #pragma unroll
    for(int cc=0;cc<4;cc++){
      bf16x8 b=*(const bf16x8*)&big[2560+(cc*16+mrow)*40+quad*8];
      h2[cc]=__builtin_amdgcn_mfma_f32_16x16x32_bf16(a,b,h2[cc],0,0,0);
    }
  }
  #pragma unroll
  for(int cc=0;cc<4;cc++){
    float bs=sb2[cc*16+mrow];
    #pragma unroll
    for(int reg=0;reg<4;reg++)
      big[5120+(r0+quad*4+reg)*72+cc*16+mrow]=f2bf(gelu_f(h2[cc][reg]+bs));
  }
  __syncthreads();

  f32x4 xac[8];
  #pragma unroll
  for(int cc=0;cc<8;cc++) xac[cc]=(f32x4){0.f,0.f,0.f,0.f};
  #pragma unroll
  for(int ks=0;ks<2;ks++){
    bf16x8 a=*(const bf16x8*)&big[5120+(r0+mrow)*72+ks*32+quad*8];
    #pragma unroll
    for(int cc=0;cc<8;cc++){
      bf16x8 b=*(const bf16x8*)&big[9728+(cc*16+mrow)*72+ks*32+quad*8];
      xac[cc]=__builtin_amdgcn_mfma_f32_16x16x32_bf16(a,b,xac[cc],0,0,0);
    }
  }
  __syncthreads();

  #pragma unroll
  for(int reg=0;reg<4;reg++){
    int rowl=r0+quad*4+reg, rowg=tok0+rowl;
    float xv[8], s=0.f, sq=0.f;
    #pragma unroll
    for(int cc=0;cc<8;cc++){
      float v=gelu_f(xac[cc][reg]+sb3[cc*16+mrow]);
      xv[cc]=v; s+=v; sq+=v*v;
    }
    #pragma unroll
    for(int m=1;m<16;m<<=1){ s+=__shfl_xor(s,m); sq+=__shfl_xor(sq,m); }
    float mu=s*(1.f/128.f);
    float var=sq*(1.f/128.f)-mu*mu;
    float rstd=rsqrtf(var+1e-5f);
    #pragma unroll
    for(int cc=0;cc<8;cc++){
      int col=cc*16+mrow;
      X[(size_t)rowg*128+col]=xv[cc];
      big[rowl*136+col]=f2bf((xv[cc]-mu)*rstd*lnw[col]+lnb[col]);
    }
  }
  __syncthreads();
  for(int th=t; th<1024; th+=256){
    int row=th>>4, seg=th&15;
    *(uint4*)&xn[(size_t)(tok0+row)*128+seg*8]=*(const uint4*)&big[row*136+seg*8];
  }
}

// ---------------- qkvg epilogue helper (shared by qkvg_kernel and mlpq tail) ----------------
// xPos via angle-addition recurrence: base (3 transcendentals) per 4-consecutive-l group,
// then (u,v) advanced with 6 FMAs per step. No loads, no tables.
__device__ __forceinline__ void qkvg_epilogue(
    int nc, f32x4 acc[2][4], u16* stg,
    int t, int mrow, int quad, int r0q, int c0q, int b, int l0, int tok0,
    u16* __restrict__ Q, u16* __restrict__ K,
    u16* __restrict__ Vt, u16* __restrict__ G)
{
  if(nc < 2){
    bool isK = (nc==1);
    float sgn = isK ? -1.f : 1.f;
    #pragma unroll
    for(int cc=0;cc<4;cc++){
      int colc = c0q + cc*16 + mrow;
      int i = (colc&31)>>1;
      float log2bs = log2f(((float)i + 12.8f)*(1.f/44.8f));
      float invf   = exp2f(-(float)i * (13.28771238f/16.f));
      float rstep  = exp2f(sgn*log2bs*(1.f/512.f));
      float c1 = cosf(invf), s1 = sinf(invf);
      #pragma unroll
      for(int rr=0;rr<2;rr++){
        int rowl0 = r0q + rr*16 + quad*4;
        float lb = (float)(l0 + rowl0);
        float sc = exp2f(sgn*log2bs*lb*(1.f/512.f));
        float ang = lb*invf;
        float u = cosf(ang)*sc, v = sinf(ang)*sc;
        #pragma unroll
        for(int reg=0;reg<4;reg++){
          int rowl = rowl0 + reg;
          float val = acc[rr][cc][reg];
          float partner = __shfl_xor(val, 1);
          float o = (colc&1) ? (val*u + partner*v) : (val*u - partner*v);
          stg[rowl*136 + colc] = f2bf(o);
          float un = (u*c1 - v*s1)*rstep;
          float vn = (u*s1 + v*c1)*rstep;
          u = un; v = vn;
        }
      }
    }
    __syncthreads();
    u16* O = isK ? K : Q;
    for(int th=t; th<1024; th+=256){
      int row=th>>4, n=(th>>2)&3, seg=th&3;
      *(uint4*)&O[(((size_t)(b*4+n)*512) + (l0+row))*32 + seg*8]
        = *(const uint4*)&stg[row*136 + n*32 + seg*8];
    }
  } else if(nc < 4){
    #pragma unroll
    for(int cc=0;cc<4;cc++){
      int colc = c0q + cc*16 + mrow;
      #pragma unroll
      for(int rr=0;rr<2;rr++){
        #pragma unroll
        for(int reg=0;reg<4;reg++){
          int rowl = r0q + rr*16 + quad*4 + reg;
          stg[colc*72 + rowl] = f2bf(acc[rr][cc][reg]);
        }
      }
    }
    __syncthreads();
    int jbase = (nc-2)*128;
    for(int th=t; th<1024; th+=256){
      int row=th>>3, seg=th&7;
      int jg = jbase + row; int n = jg>>6, j = jg&63;
      *(uint4*)&Vt[(((size_t)(b*4+n)*64) + j)*512 + l0 + seg*8]
        = *(const uint4*)&stg[row*72 + seg*8];
    }
  } else {
    #pragma unroll
    for(int cc=0;cc<4;cc++){
      int colc = c0q + cc*16 + mrow;
      #pragma unroll
      for(int rr=0;rr<2;rr++){
        #pragma unroll
        for(int reg=0;reg<4;reg++){
          int rowl = r0q + rr*16 + quad*4 + reg;
          stg[rowl*136 + colc] = f2bf(acc[rr][cc][reg]);
        }
      }
    }
    __syncthreads();
    int gc0 = (nc-4)*128;
    for(int th=t; th<1024; th+=256){
      int row=th>>4, seg=th&15;
      *(uint4*)&G[((size_t)(tok0+row))*256 + gc0 + seg*8]
        = *(const uint4*)&stg[row*136 + seg*8];
    }
  }
}

// ---------------- qkvg v3 (layer 0 only): async swizzled weight staging ----------------
__global__ __launch_bounds__(256) void qkvg_kernel(
    const u16* __restrict__ A, const u16* __restrict__ Wt,
    u16* __restrict__ Q, u16* __restrict__ K,
    u16* __restrict__ Vt, u16* __restrict__ G)
{
  __shared__ u16 sW[128*128];      // 32 KB swizzled weights; reused as epilogue staging
  u16* stg = sW;
  int t = threadIdx.x, lane = t&63, wid = t>>6;
  int mrow = lane&15, quad = lane>>4;
  int srow = lane>>4, phys16l = lane&15;
  int r0q = (wid>>1)*32, c0q = (wid&1)*64;
  int tok0 = blockIdx.x*64;
  int b = tok0>>9, l0 = tok0&511;

  bf16x8 a0f[4], a1f[4];
  #pragma unroll
  for(int ks=0; ks<4; ks++){
    a0f[ks] = *(const bf16x8*)&A[(size_t)(tok0+r0q+mrow)*128 + ks*32+quad*8];
    a1f[ks] = *(const bf16x8*)&A[(size_t)(tok0+r0q+16+mrow)*128 + ks*32+quad*8];
  }

  for(int ch=0; ch<3; ch++){
    int nc = blockIdx.y*3 + ch;   // 0..5
    if(ch) __syncthreads();
    STAGE_TILE(sW, Wt + (size_t)nc*16384, 128, 0, wid, srow, phys16l);
    __syncthreads();

    f32x4 acc[2][4];
    #pragma unroll
    for(int rr=0;rr<2;rr++)
      #pragma unroll
      for(int cc=0;cc<4;cc++) acc[rr][cc] = (f32x4){0.f,0.f,0.f,0.f};
    #pragma unroll
    for(int ks=0; ks<4; ks++){
      #pragma unroll
      for(int cc=0; cc<4; cc++){
        bf16x8 bb = *(const bf16x8*)&sW[(c0q+cc*16+mrow)*128 + (((ks*4+quad)^mrow)<<3)];
        acc[0][cc] = __builtin_amdgcn_mfma_f32_16x16x32_bf16(a0f[ks],bb,acc[0][cc],0,0,0);
        acc[1][cc] = __builtin_amdgcn_mfma_f32_16x16x32_bf16(a1f[ks],bb,acc[1][cc],0,0,0);
      }
    }
    __syncthreads();
    qkvg_epilogue(nc, acc, stg, t, mrow, quad, r0q, c0q, b, l0, tok0, Q, K, Vt, G);
  }
}

// ---------------- fused MLP + qkvg(next layer): xn never touches HBM ----------------
__global__ __launch_bounds__(256) void mlpq_kernel(
    const u16* __restrict__ Gated, const u16* __restrict__ Wo,
    const u16* __restrict__ W1t, const float* __restrict__ b1,
    const u16* __restrict__ W2t, const float* __restrict__ b2,
    const float* __restrict__ Xin,
    const float* __restrict__ ln2w, const float* __restrict__ ln2b,
    const float* __restrict__ ln1w, const float* __restrict__ ln1b,
    float* __restrict__ Xout,
    const u16* __restrict__ Wq,   // next layer qkvg weights (nullptr on last layer)
    u16* __restrict__ Q, u16* __restrict__ K,
    u16* __restrict__ Vt, u16* __restrict__ G)
{
  __shared__ u16 sW[128*128];   // 32768 B: swizzled weights / fp32 X staging / qkvg epilogue stg
  __shared__ u16 sT[64*136];    // 17408 B: Z / H / xn (kept in LDS)
  int t=threadIdx.x, lane=t&63, wid=t>>6, mrow=lane&15, quad=lane>>4, r0=wid*16;
  int tok0=blockIdx.x*64;
  int srow = lane>>4, phys16l = lane&15;

  // gfrag direct from global (own rows)
  bf16x8 gfrag[8];
  #pragma unroll
  for(int ks=0;ks<8;ks++)
    gfrag[ks]=*(const bf16x8*)&Gated[(size_t)(tok0+r0+mrow)*256 + ks*32+quad*8];

  // ---- wo: K=256 in 2 halves (full N=128 resident)
  f32x4 yac[8];
  #pragma unroll
  for(int ch=0;ch<8;ch++) yac[ch]=(f32x4){0.f,0.f,0.f,0.f};
  STAGE_TILE(sW, Wo, 256, 0, wid, srow, phys16l);
  __syncthreads();
  #pragma unroll
  for(int kh=0; kh<2; kh++){
    #pragma unroll
    for(int ch=0;ch<8;ch++){
      #pragma unroll
      for(int ks=0;ks<4;ks++){
        bf16x8 b=*(const bf16x8*)&sW[(ch*16+mrow)*128 + (((ks*4+quad)^mrow)<<3)];
        yac[ch]=__builtin_amdgcn_mfma_f32_16x16x32_bf16(gfrag[kh*4+ks],b,yac[ch],0,0,0);
      }
    }
    if(kh==0){
      __syncthreads();
      STAGE_TILE(sW, Wo, 256, 128, wid, srow, phys16l);
      __syncthreads();
    }
  }

  // ---- Y = yac + Xin (regs); LN2 -> Z bf16 into sT (own rows)
  float yv[8][4];
  #pragma unroll
  for(int reg=0;reg<4;reg++){
    int rowl=r0+quad*4+reg, rowg=tok0+rowl;
    float s=0.f, sq=0.f;
    #pragma unroll
    for(int ch=0;ch<8;ch++){
      float v=yac[ch][reg]+Xin[(size_t)rowg*128+ch*16+mrow];
      yv[ch][reg]=v; s+=v; sq+=v*v;
    }
    #pragma unroll
    for(int m=1;m<16;m<<=1){ s+=__shfl_xor(s,m); sq+=__shfl_xor(sq,m); }
    float mu=s*(1.f/128.f);
    float var=sq*(1.f/128.f)-mu*mu;
    float rstd=rsqrtf(var+1e-5f);
    #pragma unroll
    for(int ch=0;ch<8;ch++){
      int col=ch*16+mrow;
      sT[rowl*136+col]=f2bf((yv[ch][reg]-mu)*rstd*ln2w[col]+ln2b[col]);
    }
  }
  bf16x8 az[4];
  #pragma unroll
  for(int ks=0;ks<4;ks++) az[ks]=*(const bf16x8*)&sT[(r0+mrow)*136+ks*32+quad*8];
  __syncthreads();

  // ---- ffn1: N=256 in 2 halves of 128 cols (full K=128 resident); H-half -> sT
  bf16x8 hfrag[8];
  #pragma unroll
  for(int nh=0; nh<2; nh++){
    STAGE_TILE(sW, W1t + (size_t)nh*16384, 128, 0, wid, srow, phys16l);
    __syncthreads();
    f32x4 hac[8];
    #pragma unroll
    for(int ch=0;ch<8;ch++) hac[ch]=(f32x4){0.f,0.f,0.f,0.f};
    #pragma unroll
    for(int ch=0;ch<8;ch++){
      #pragma unroll
      for(int ks=0;ks<4;ks++){
        bf16x8 b=*(const bf16x8*)&sW[(ch*16+mrow)*128 + (((ks*4+quad)^mrow)<<3)];
        hac[ch]=__builtin_amdgcn_mfma_f32_16x16x32_bf16(az[ks],b,hac[ch],0,0,0);
      }
    }
    #pragma unroll
    for(int ch=0;ch<8;ch++){
      float bs=b1[nh*128+ch*16+mrow];
      #pragma unroll
      for(int reg=0;reg<4;reg++)
        sT[(r0+quad*4+reg)*136 + ch*16+mrow]=f2bf(gelu_f(hac[ch][reg]+bs));
    }
    #pragma unroll
    for(int ks=0;ks<4;ks++) hfrag[nh*4+ks]=*(const bf16x8*)&sT[(r0+mrow)*136+ks*32+quad*8];
    __syncthreads();
  }

  // ---- ffn2: K=256 in 2 halves (full N=128 resident)
  f32x4 xac[8];
  #pragma unroll
  for(int ch=0;ch<8;ch++) xac[ch]=(f32x4){0.f,0.f,0.f,0.f};
  STAGE_TILE(sW, W2t, 256, 0, wid, srow, phys16l);
  __syncthreads();
  #pragma unroll
  for(int kh=0; kh<2; kh++){
    #pragma unroll
    for(int ch=0;ch<8;ch++){
      #pragma unroll
      for(int ks=0;ks<4;ks++){
        bf16x8 b=*(const bf16x8*)&sW[(ch*16+mrow)*128 + (((ks*4+quad)^mrow)<<3)];
        xac[ch]=__builtin_amdgcn_mfma_f32_16x16x32_bf16(hfrag[kh*4+ks],b,xac[ch],0,0,0);
      }
    }
    __syncthreads();
    if(kh==0){
      STAGE_TILE(sW, W2t, 256, 128, wid, srow, phys16l);
      __syncthreads();
    }
  }

  // ---- epilogue: X = xac + b2 + Y; LN1(next) -> sT (xn, LDS-resident)
  float* fst = (float*)sW;       // [64][128] = 32768 B
  #pragma unroll
  for(int reg=0;reg<4;reg++){
    int rowl=r0+quad*4+reg;
    float xv[8], s=0.f, sq=0.f;
    #pragma unroll
    for(int ch=0;ch<8;ch++){
      float v=xac[ch][reg]+b2[ch*16+mrow]+yv[ch][reg];
      xv[ch]=v; s+=v; sq+=v*v;
    }
    #pragma unroll
    for(int m=1;m<16;m<<=1){ s+=__shfl_xor(s,m); sq+=__shfl_xor(sq,m); }
    float mu=s*(1.f/128.f);
    float var=sq*(1.f/128.f)-mu*mu;
    float rstd=rsqrtf(var+1e-5f);
    #pragma unroll
    for(int ch=0;ch<8;ch++){
      int col=ch*16+mrow;
      fst[rowl*128+col]=xv[ch];
      sT[rowl*136+col]=f2bf((xv[ch]-mu)*rstd*ln1w[col]+ln1b[col]);
    }
  }
  __syncthreads();
  for(int th=t; th<2048; th+=256){
    int row=th>>5, c4=(th&31)*4;
    *(float4*)&Xout[(size_t)(tok0+row)*128+c4]=*(const float4*)&fst[row*128+c4];
  }

  if(!Wq) return;

  // ---- fused qkvg for next layer: A-frags from sT (xn in LDS)
  int r0q = (wid>>1)*32, c0q = (wid&1)*64;
  int b = tok0>>9, l0 = tok0&511;
  bf16x8 a0f[4], a1f[4];
  #pragma unroll
  for(int ks=0; ks<4; ks++){
    a0f[ks] = *(const bf16x8*)&sT[(r0q+mrow)*136 + ks*32+quad*8];
    a1f[ks] = *(const bf16x8*)&sT[(r0q+16+mrow)*136 + ks*32+quad*8];
  }
  __syncthreads();   // Xout reads of fst(sW) done before STAGE overwrites

  for(int nc=0; nc<6; nc++){
    if(nc) __syncthreads();   // prev epilogue's stg reads done
    STAGE_TILE(sW, Wq + (size_t)nc*16384, 128, 0, wid, srow, phys16l);
    __syncthreads();

    f32x4 acc[2][4];
    #pragma unroll
    for(int rr=0;rr<2;rr++)
      #pragma unroll
      for(int cc=0;cc<4;cc++) acc[rr][cc] = (f32x4){0.f,0.f,0.f,0.f};
    #pragma unroll
    for(int ks=0; ks<4; ks++){
      #pragma unroll
      for(int cc=0; cc<4; cc++){
        bf16x8 bb = *(const bf16x8*)&sW[(c0q+cc*16+mrow)*128 + (((ks*4+quad)^mrow)<<3)];
        acc[0][cc] = __builtin_amdgcn_mfma_f32_16x16x32_bf16(a0f[ks],bb,acc[0][cc],0,0,0);
        acc[1][cc] = __builtin_amdgcn_mfma_f32_16x16x32_bf16(a1f[ks],bb,acc[1][cc],0,0,0);
      }
    }
    __syncthreads();
    qkvg_epilogue(nc, acc, sW, t, mrow, quad, r0q, c0q, b, l0, tok0, Q, K, Vt, G);
  }
}

// ---------------- retention v3: double-buffered K/Vt prefetch + groupnorm + silu gate ----------------
__global__ __launch_bounds__(256) void retmfma_kernel(
    const u16* __restrict__ Q, const u16* __restrict__ K,
    const u16* __restrict__ Vt, const u16* __restrict__ G,
    const float* __restrict__ gnw, const float* __restrict__ gnb,
    u16* __restrict__ Gated, float4 log2g)
{
  int idx = blockIdx.x;
  int bn = ((idx>>6)<<3) | (idx&7);
  int lt = (idx>>3)&7;
  int n = bn & 3, b = bn >> 2;
  float lg2g = (n==0)?log2g.x:(n==1)?log2g.y:(n==2)?log2g.z:log2g.w;
  __shared__ u16 sK[2][64][40];
  __shared__ u16 sVt[2][64][72];
  __shared__ u16 sS[64][72];
  int t = threadIdx.x, lane = t&63, wid = t>>6;
  int mrow = lane&15, quad = lane>>4;
  int r0 = wid*16;

  bf16x8 qa = *(const bf16x8*)&Q[((size_t)bn*512 + lt*64 + r0+mrow)*32 + quad*8];

  f32x4 oacc[4];
  #pragma unroll
  for(int cc=0;cc<4;cc++) oacc[cc] = (f32x4){0.f,0.f,0.f,0.f};
  float gp1 = exp2f(lg2g), gp2 = gp1*gp1, gp3 = gp2*gp1;
  float gpow[4] = {1.f, gp1, gp2, gp3};
  float gw[4], gb[4];
  #pragma unroll
  for(int cc=0;cc<4;cc++){ gw[cc]=gnw[n*64+cc*16+mrow]; gb[cc]=gnb[n*64+cc*16+mrow]; }
  int rowl0 = lt*64 + r0 + quad*4;

  int krow = t>>2, kc8 = (t&3)*8;
  int vrow = t>>3, vc8 = (t&7)*8;

  {
    *(uint4*)&sK[0][krow][kc8] = *(const uint4*)&K[((size_t)bn*512 + krow)*32 + kc8];
    *(uint4*)&sVt[0][vrow][vc8]    = *(const uint4*)&Vt[((size_t)bn*64 + vrow)*512    + vc8];
    *(uint4*)&sVt[0][vrow+32][vc8] = *(const uint4*)&Vt[((size_t)bn*64 + vrow+32)*512 + vc8];
  }
  __syncthreads();

  for(int mt=0; mt<=lt; mt++){
    int cur = mt&1;
    if(mt<lt){
      int nx = cur^1, m1 = mt+1;
      *(uint4*)&sK[nx][krow][kc8] = *(const uint4*)&K[((size_t)bn*512 + m1*64 + krow)*32 + kc8];
      *(uint4*)&sVt[nx][vrow][vc8]    = *(const uint4*)&Vt[((size_t)bn*64 + vrow)*512    + m1*64 + vc8];
      *(uint4*)&sVt[nx][vrow+32][vc8] = *(const uint4*)&Vt[((size_t)bn*64 + vrow+32)*512 + m1*64 + vc8];
    }
    f32x4 sacc[4];
    #pragma unroll
    for(int cc=0;cc<4;cc++){
      bf16x8 bb = *(const bf16x8*)&sK[cur][cc*16+mrow][quad*8];
      sacc[cc] = __builtin_amdgcn_mfma_f32_16x16x32_bf16(qa,bb,(f32x4){0.f,0.f,0.f,0.f},0,0,0);
    }
    #pragma unroll
    for(int cc=0;cc<4;cc++){
      int colm = mt*64 + cc*16 + mrow;
      int d0 = rowl0 - colm;
      float w0 = exp2f(lg2g*(float)d0);
      #pragma unroll
      for(int reg=0;reg<4;reg++){
        float w = (d0+reg>=0) ? w0*gpow[reg] : 0.f;
        sS[r0+quad*4+reg][cc*16+mrow] = f2bf(sacc[cc][reg]*w);
      }
    }
    __syncthreads();
    #pragma unroll
    for(int ks=0;ks<2;ks++){
      bf16x8 a = *(const bf16x8*)&sS[r0+mrow][ks*32+quad*8];
      #pragma unroll
      for(int cc=0;cc<4;cc++){
        bf16x8 bb = *(const bf16x8*)&sVt[cur][cc*16+mrow][ks*32+quad*8];
        oacc[cc] = __builtin_amdgcn_mfma_f32_16x16x32_bf16(a,bb,oacc[cc],0,0,0);
      }
    }
    __syncthreads();
  }

  #pragma unroll
  for(int reg=0;reg<4;reg++){
    float s=0.f, sq=0.f;
    #pragma unroll
    for(int cc=0;cc<4;cc++){ float v=oacc[cc][reg]; s+=v; sq+=v*v; }
    #pragma unroll
    for(int m=1;m<16;m<<=1){ s+=__shfl_xor(s,m); sq+=__shfl_xor(sq,m); }
    float mu = s*(1.f/64.f);
    float var = sq*(1.f/64.f) - mu*mu;
    float rn = rsqrtf(var + 1e-5f);
    int rowl = r0 + quad*4 + reg;
    int l = lt*64 + rowl;
    size_t gbase = ((size_t)(b*512 + l))*256 + n*64;
    #pragma unroll
    for(int cc=0;cc<4;cc++){
      float gg = bf2f(G[gbase + cc*16+mrow]);
      float gate = gg/(1.f+expf(-gg));
      sS[rowl][cc*16+mrow] = f2bf(gate*((oacc[cc][reg]-mu)*rn*gw[cc] + gb[cc]));
    }
  }
  __syncthreads();
  for(int th=t; th<512; th+=256){
    int row=th>>3, seg=th&7;
    *(uint4*)&Gated[((size_t)(b*512 + lt*64 + row))*256 + n*64 + seg*8]
      = *(const uint4*)&sS[row][seg*8];
  }
}

// ---------------- decoder (MFMA): softmax(gelu(X@w1+b1)@w2+b2) ----------------
__global__ __launch_bounds__(256) void dec_kernel(
    const float* __restrict__ X, const u16* __restrict__ W1t,
    const float* __restrict__ b1, const float* __restrict__ w2,
    const float* __restrict__ b2, float* __restrict__ out)
{
  __shared__ u16 sA[64][136];
  __shared__ u16 sW[64][136];
  __shared__ float sH[64][68];
  __shared__ float sL[64*20];
  __shared__ float sw2[64*20];
  __shared__ float sb2[20];
  int t = threadIdx.x, lane = t&63, wid = t>>6;
  int mrow = lane&15, quad = lane>>4;
  int tok0 = blockIdx.x*64;

  for(int th=t; th<2048; th+=256){
    int row=th>>5, c4=(th&31)*4;
    float4 v = *(const float4*)&X[(size_t)(tok0+row)*128 + c4];
    ushort4 p; p.x=f2bf(v.x); p.y=f2bf(v.y); p.z=f2bf(v.z); p.w=f2bf(v.w);
    *(ushort4*)&sA[row][c4] = p;
  }
  for(int th=t; th<1024; th+=256){
    int row=th>>4, c8=(th&15)*8;
    *(uint4*)&sW[row][c8] = *(const uint4*)&W1t[(size_t)row*128 + c8];
  }
  for(int i=t;i<1280;i+=256) sw2[i]=w2[i];
  if(t<20) sb2[t]=b2[t];
  __syncthreads();

  int r0 = wid*16;
  f32x4 acc[4];
  #pragma unroll
  for(int cc=0;cc<4;cc++) acc[cc] = (f32x4){0.f,0.f,0.f,0.f};
  #pragma unroll
  for(int ks=0; ks<4; ks++){
    int koff = ks*32 + quad*8;
    bf16x8 a = *(const bf16x8*)&sA[r0+mrow][koff];
    #pragma unroll
    for(int cc=0; cc<4; cc++){
      bf16x8 b = *(const bf16x8*)&sW[cc*16+mrow][koff];
      acc[cc] = __builtin_amdgcn_mfma_f32_16x16x32_bf16(a,b,acc[cc],0,0,0);
    }
  }
  #pragma unroll
  for(int cc=0;cc<4;cc++){
    int col = cc*16 + mrow;
    float bb = b1[col];
    #pragma unroll
    for(int reg=0;reg<4;reg++){
      sH[r0 + quad*4 + reg][col] = gelu_f(acc[cc][reg] + bb);
    }
  }
  __syncthreads();

  for(int task=t; task<1280; task+=256){
    int tk = task/20, o = task - tk*20;
    float a = sb2[o];
    for(int k=0;k<64;k++) a += sH[tk][k]*sw2[k*20+o];
    sL[tk*20+o] = a;
  }
  __syncthreads();
  if(t < 64){
    float mx = -1e30f;
    #pragma unroll
    for(int o=0;o<20;o++) mx = fmaxf(mx, sL[t*20+o]);
    float sum = 0.f;
    float e[20];
    #pragma unroll
    for(int o=0;o<20;o++){ e[o]=expf(sL[t*20+o]-mx); sum += e[o]; }
    float inv = 1.f/sum;
    #pragma unroll
    for(int o=0;o<20;o++) sL[t*20+o] = e[o]*inv;
  }
  __syncthreads();
  for(int th=t; th<1280; th+=256){
    out[(size_t)tok0*20 + th] = sL[th];
  }
}

extern "C" void kernel_launch(void* const* d_in, const int* in_sizes, int n_in,
                              void* d_out, int out_size, void* d_ws, size_t ws_size,
                              hipStream_t stream) {
  (void)in_sizes; (void)n_in; (void)out_size; (void)ws_size;
  const float* x      = (const float*)d_in[0];
  const float* rem_w1 = (const float*)d_in[1];
  const float* rem_b1 = (const float*)d_in[2];
  const float* rem_w2 = (const float*)d_in[3];
  const float* rem_b2 = (const float*)d_in[4];
  const float* rem_w3 = (const float*)d_in[5];
  const float* rem_b3 = (const float*)d_in[6];
  const float* wq     = (const float*)d_in[7];
  const float* wk     = (const float*)d_in[8];
  const float* wv     = (const float*)d_in[9];
  const float* wg     = (const float*)d_in[10];
  const float* wo     = (const float*)d_in[11];
  const float* gn_w   = (const float*)d_in[12];
  const float* gn_b   = (const float*)d_in[13];
  const float* ln1_w  = (const float*)d_in[14];
  const float* ln1_b  = (const float*)d_in[15];
  const float* ln2_w  = (const float*)d_in[16];
  const float* ln2_b  = (const float*)d_in[17];
  const float* ffn_w1 = (const float*)d_in[18];
  const float* ffn_b1 = (const float*)d_in[19];
  const float* ffn_w2 = (const float*)d_in[20];
  const float* ffn_b2 = (const float*)d_in[21];
  const float* dec_w1 = (const float*)d_in[22];
  const float* dec_b1 = (const float*)d_in[23];
  const float* dec_w2 = (const float*)d_in[24];
  const float* dec_b2 = (const float*)d_in[25];
  float* outp = (float*)d_out;

  const size_t S128 = (size_t)BT*128;
  const size_t S256 = (size_t)BT*256;
  float* ws = (float*)d_ws;
  float* Xb = ws;                  // residual X        (S128 f32)
  u16*  Qb16    = (u16*)(Xb + S128);     // Q bf16 head-layout (BT*32)
  u16*  Kb16    = Qb16 + (size_t)BT*32;
  u16*  Vt16    = Kb16 + (size_t)BT*32;  // V bf16 transposed (BT*64)
  u16*  XnBf    = Vt16 + (size_t)BT*64;  // LN out bf16 (layer-0 only)
  u16*  GBf     = XnBf + S128;           // G bf16        (S256)
  u16*  GatedBf = GBf + S256;            // gated        (S256)
  u16*  WtBf    = GatedBf + S256;        // bf16 weights  (804864 u16)

  double lgA = log(1.0/32.0), lgB = log(1.0/512.0);
  float4 l2g;
  {
    double g0 = 1.0 - exp(lgA + 0.0*(lgB-lgA)/3.0);
    double g1 = 1.0 - exp(lgA + 1.0*(lgB-lgA)/3.0);
    double g2 = 1.0 - exp(lgA + 2.0*(lgB-lgA)/3.0);
    double g3 = 1.0 - exp(lgA + 3.0*(lgB-lgA)/3.0);
    l2g.x = (float)(log(g0)/log(2.0));
    l2g.y = (float)(log(g1)/log(2.0));
    l2g.z = (float)(log(g2)/log(2.0));
    l2g.w = (float)(log(g3)/log(2.0));
  }

  wconv_kernel<<<3144, 256, 0, stream>>>(wq, wk, wv, wg, wo, ffn_w1, ffn_w2, dec_w1,
                                         rem_w2, rem_w3, WtBf);
  embed_kernel<<<BT/64, 256, 0, stream>>>(x, rem_w1, rem_b1, rem_b2, rem_b3,
                                          WtBf+794624, ln1_w, ln1_b, Xb, XnBf);
  qkvg_kernel<<<dim3(BT/64,2), 256, 0, stream>>>(XnBf, WtBf, Qb16, Kb16, Vt16, GBf);

  for(int li=0; li<4; li++){
    u16* Wt_l = WtBf + (size_t)li*196608;
    const float* gnw_l = gn_w + (size_t)li*VDIM;
    const float* gnb_l = gn_b + (size_t)li*VDIM;
    const float* l2w = ln2_w + (size_t)li*HID, *l2b = ln2_b + (size_t)li*HID;
    const float* f1b = ffn_b1 + (size_t)li*FFND;
    const float* f2b = ffn_b2 + (size_t)li*HID;
    int nli = (li+1)&3;
    const float* n1w = ln1_w + (size_t)nli*HID, *n1b = ln1_b + (size_t)nli*HID;
    const u16* Wq_next = (li<3) ? (WtBf + (size_t)(li+1)*196608) : nullptr;

    retmfma_kernel<<<2048, 256, 0, stream>>>(Qb16, Kb16, Vt16, GBf, gnw_l, gnb_l, GatedBf, l2g);
    mlpq_kernel<<<BT/64, 256, 0, stream>>>(
        GatedBf, Wt_l+98304, Wt_l+131072, f1b, Wt_l+163840, f2b,
        Xb, l2w, l2b, n1w, n1b, Xb,
        Wq_next, Qb16, Kb16, Vt16, GBf);
  }

  dec_kernel<<<BT/64, 256, 0, stream>>>(Xb, WtBf+786432, dec_b1, dec_w2, dec_b2, outp);
}

// Round 18
// 452.412 us; speedup vs baseline: 1.2421x; 1.0066x over previous
//
#include <hip/hip_runtime.h>
#include <math.h>
#include <cmath>

#define SEQ   512
#define NBATCH 64
#define BT    32768      // 64*512 tokens
#define HID   128
#define NHEAD 4
#define HD    32
#define VHD   64
#define VDIM  256
#define FFND  256

typedef __attribute__((ext_vector_type(8))) short bf16x8;
typedef __attribute__((ext_vector_type(4))) float f32x4;
typedef unsigned short u16;

__device__ __forceinline__ float gelu_f(float x){ return 0.5f*x*(1.f+erff(x*0.70710678118f)); }

__device__ __forceinline__ u16 f2bf(float f){
  union{float f; unsigned u;} v; v.f = f;
  unsigned r = v.u + 0x7FFF + ((v.u>>16)&1);
  return (u16)(r>>16);
}
__device__ __forceinline__ float bf2f(u16 u){
  union{unsigned u; float f;} v; v.u = ((unsigned)u)<<16; return v.f;
}

// async 16B global->LDS (HW scatters lane i at ldsbase + i*16)
__device__ __forceinline__ void gload16(const void* g, void* l){
  __builtin_amdgcn_global_load_lds(
      (const __attribute__((address_space(1))) unsigned*)g,
      (__attribute__((address_space(3))) unsigned*)l, 16, 0, 0);
}

// stage a 128-row x 128-u16 weight tile, XOR-swizzled (phys16 = log16 ^ (row&15))
// B-frag read: logical (row, ks*32+quad*8) -> sW[row*128 + (((ks*4+quad)^(row&15))<<3)]
#define STAGE_TILE(dst, base, strideU16, colOffU16, wid_, srow_, phys16l_)      \
  do{                                                                           \
    _Pragma("unroll")                                                           \
    for(int it_=0; it_<8; it_++){                                               \
      int blk_ = (wid_)*8 + it_;                                                \
      int row_ = blk_*4 + (srow_);                                              \
      int log16_ = (phys16l_) ^ (row_&15);                                      \
      gload16((base) + (size_t)row_*(strideU16) + (colOffU16) + log16_*8,       \
              &(dst)[blk_*512]);                                                \
    }                                                                           \
  }while(0)

// ---------------- weight convert + transpose -> bf16 Wt[N][K] ----------------
// per-layer region (196608 u16): [0)qkvg 768x128  [98304)wo 128x256  [131072)f1 256x128  [163840)f2 128x256
// tail: 786432 dec_w1t 64x128 (8192); 794624 rem_w2t 64x32 (2048); 796672 rem_w3t 128x64 (8192). total 804864
__global__ __launch_bounds__(256) void wconv_kernel(
    const float* __restrict__ wq, const float* __restrict__ wk,
    const float* __restrict__ wv, const float* __restrict__ wg,
    const float* __restrict__ wo, const float* __restrict__ f1,
    const float* __restrict__ f2, const float* __restrict__ dw1,
    const float* __restrict__ w2e, const float* __restrict__ w3e,
    u16* __restrict__ Wt)
{
  int idx = blockIdx.x*256 + threadIdx.x;   // 0..804863
  if(idx >= 786432){
    int q = idx - 786432;
    if(q < 8192){ int col=q>>7, h=q&127; Wt[idx]=f2bf(dw1[h*64+col]); }
    else if(q < 10240){ int p=q-8192; int row=p>>5, col=p&31; Wt[idx]=f2bf(w2e[col*64+row]); }
    else { int p=q-10240; int row=p>>6, col=p&63; Wt[idx]=f2bf(w3e[col*128+row]); }
    return;
  }
  int layer = idx / 196608;
  int r = idx - layer*196608;
  u16* W = Wt + (size_t)layer*196608;
  const float* wq_l = wq + (size_t)layer*16384;
  const float* wk_l = wk + (size_t)layer*16384;
  const float* wv_l = wv + (size_t)layer*32768;
  const float* wg_l = wg + (size_t)layer*32768;
  const float* wo_l = wo + (size_t)layer*32768;
  const float* f1_l = f1 + (size_t)layer*32768;
  const float* f2_l = f2 + (size_t)layer*32768;
  float v;
  if(r < 98304){
    int col = r>>7, h = r&127;
    if(col<128){ int n=col>>5, d=col&31; v = wq_l[(n*128+h)*32+d]; }
    else if(col<256){ int c=col-128, n=c>>5, d=c&31; v = wk_l[(n*128+h)*32+d]; }
    else if(col<512){ int c=col-256, n=c>>6, j=c&63; v = wv_l[(n*128+h)*64+j]; }
    else { int p=col-512; v = wg_l[h*256+p]; }
    W[r] = f2bf(v);
  } else if(r < 131072){
    int q = r-98304; int col=q>>8, k=q&255;
    W[r] = f2bf(wo_l[k*128+col]);
  } else if(r < 163840){
    int q = r-131072; int col=q>>7, h=q&127;
    W[r] = f2bf(f1_l[h*256+col]);
  } else {
    int q = r-163840; int col=q>>8, k=q&255;
    W[r] = f2bf(f2_l[k*128+col]);
  }
}

// ---------------- embed (MFMA) + fused layer-0 LN1 ----------------
__global__ __launch_bounds__(256) void embed_kernel(
    const float* __restrict__ x,
    const float* __restrict__ w1, const float* __restrict__ b1,
    const float* __restrict__ b2, const float* __restrict__ b3,
    const u16* __restrict__ W23t,     // w2t[64][32] at 0, w3t[128][64] at 2048
    const float* __restrict__ lnw, const float* __restrict__ lnb,
    float* __restrict__ X, u16* __restrict__ xn)
{
  __shared__ float sx[64][6];
  __shared__ float sw1[160], sb1[32], sb2[64], sb3[128];
  __shared__ u16 big[18944];
  int t=threadIdx.x, lane=t&63, wid=t>>6, mrow=lane&15, quad=lane>>4, r0=wid*16;
  int tok0=blockIdx.x*64;

  for(int i=t;i<320;i+=256) sx[i/5][i%5]=x[(size_t)tok0*5+i];
  for(int i=t;i<160;i+=256) sw1[i]=w1[i];
  if(t<32) sb1[t]=b1[t];
  if(t<64) sb2[t]=b2[t];
  if(t<128) sb3[t]=b3[t];
  for(int c=t;c<256;c+=256){ int row=c>>2, c8=(c&3)*8;
    *(uint4*)&big[2560+row*40+c8]=*(const uint4*)&W23t[row*32+c8]; }
  for(int c=t;c<1024;c+=256){ int row=c>>3, c8=(c&7)*8;
    *(uint4*)&big[9728+row*72+c8]=*(const uint4*)&W23t[2048+row*64+c8]; }
  __syncthreads();

  for(int task=t; task<2048; task+=256){
    int tok=task>>5, j=task&31;
    float a=sb1[j];
    #pragma unroll
    for(int i=0;i<5;i++) a+=sx[tok][i]*sw1[i*32+j];
    big[tok*40+j]=f2bf(gelu_f(a));
  }
  __syncthreads();

  f32x4 h2[4];
  #pragma unroll
  for(int cc=0;cc<4;cc++) h2[cc]=(f32x4){0.f,0.f,0.f,0.f};
  {
    bf16x8 a=*(const bf16x8*)&big[(r0+mrow)*40+quad*8];
    #pragma unroll
    for(int cc=0;cc<4;cc++){
      bf16x8 b=*(const bf16x8*)&big[2560+(cc*16+mrow)*40+quad*8];
      h2[cc]=__builtin_amdgcn_mfma_f32_16x16x32_bf16(a,b,h2[cc],0,0,0);
    }
  }
  #pragma unroll
  for(int cc=0;cc<4;cc++){
    float bs=sb2[cc*16+mrow];
    #pragma unroll
    for(int reg=0;reg<4;reg++)
      big[5120+(r0+quad*4+reg)*72+cc*16+mrow]=f2bf(gelu_f(h2[cc][reg]+bs));
  }
  __syncthreads();

  f32x4 xac[8];
  #pragma unroll
  for(int cc=0;cc<8;cc++) xac[cc]=(f32x4){0.f,0.f,0.f,0.f};
  #pragma unroll
  for(int ks=0;ks<2;ks++){
    bf16x8 a=*(const bf16x8*)&big[5120+(r0+mrow)*72+ks*32+quad*8];
    #pragma unroll
    for(int cc=0;cc<8;cc++){
      bf16x8 b=*(const bf16x8*)&big[9728+(cc*16+mrow)*72+ks*32+quad*8];
      xac[cc]=__builtin_amdgcn_mfma_f32_16x16x32_bf16(a,b,xac[cc],0,0,0);
    }
  }
  __syncthreads();

  #pragma unroll
  for(int reg=0;reg<4;reg++){
    int rowl=r0+quad*4+reg, rowg=tok0+rowl;
    float xv[8], s=0.f, sq=0.f;
    #pragma unroll
    for(int cc=0;cc<8;cc++){
      float v=gelu_f(xac[cc][reg]+sb3[cc*16+mrow]);
      xv[cc]=v; s+=v; sq+=v*v;
    }
    #pragma unroll
    for(int m=1;m<16;m<<=1){ s+=__shfl_xor(s,m); sq+=__shfl_xor(sq,m); }
    float mu=s*(1.f/128.f);
    float var=sq*(1.f/128.f)-mu*mu;
    float rstd=rsqrtf(var+1e-5f);
    #pragma unroll
    for(int cc=0;cc<8;cc++){
      int col=cc*16+mrow;
      X[(size_t)rowg*128+col]=xv[cc];
      big[rowl*136+col]=f2bf((xv[cc]-mu)*rstd*lnw[col]+lnb[col]);
    }
  }
  __syncthreads();
  for(int th=t; th<1024; th+=256){
    int row=th>>4, seg=th&15;
    *(uint4*)&xn[(size_t)(tok0+row)*128+seg*8]=*(const uint4*)&big[row*136+seg*8];
  }
}

// ---------------- qkvg epilogue helper (shared by qkvg_kernel and mlpq tail) ----------------
// xPos via angle-addition recurrence: base (3 transcendentals) per 4-consecutive-l group,
// then (u,v) advanced with 6 FMAs per step. No loads, no tables.
__device__ __forceinline__ void qkvg_epilogue(
    int nc, f32x4 acc[2][4], u16* stg,
    int t, int mrow, int quad, int r0q, int c0q, int b, int l0, int tok0,
    u16* __restrict__ Q, u16* __restrict__ K,
    u16* __restrict__ Vt, u16* __restrict__ G)
{
  if(nc < 2){
    bool isK = (nc==1);
    float sgn = isK ? -1.f : 1.f;
    #pragma unroll
    for(int cc=0;cc<4;cc++){
      int colc = c0q + cc*16 + mrow;
      int i = (colc&31)>>1;
      float log2bs = log2f(((float)i + 12.8f)*(1.f/44.8f));
      float invf   = exp2f(-(float)i * (13.28771238f/16.f));
      float rstep  = exp2f(sgn*log2bs*(1.f/512.f));
      float c1 = cosf(invf), s1 = sinf(invf);
      #pragma unroll
      for(int rr=0;rr<2;rr++){
        int rowl0 = r0q + rr*16 + quad*4;
        float lb = (float)(l0 + rowl0);
        float sc = exp2f(sgn*log2bs*lb*(1.f/512.f));
        float ang = lb*invf;
        float u = cosf(ang)*sc, v = sinf(ang)*sc;
        #pragma unroll
        for(int reg=0;reg<4;reg++){
          int rowl = rowl0 + reg;
          float val = acc[rr][cc][reg];
          float partner = __shfl_xor(val, 1);
          float o = (colc&1) ? (val*u + partner*v) : (val*u - partner*v);
          stg[rowl*136 + colc] = f2bf(o);
          float un = (u*c1 - v*s1)*rstep;
          float vn = (u*s1 + v*c1)*rstep;
          u = un; v = vn;
        }
      }
    }
    __syncthreads();
    u16* O = isK ? K : Q;
    for(int th=t; th<1024; th+=256){
      int row=th>>4, n=(th>>2)&3, seg=th&3;
      *(uint4*)&O[(((size_t)(b*4+n)*512) + (l0+row))*32 + seg*8]
        = *(const uint4*)&stg[row*136 + n*32 + seg*8];
    }
  } else if(nc < 4){
    #pragma unroll
    for(int cc=0;cc<4;cc++){
      int colc = c0q + cc*16 + mrow;
      #pragma unroll
      for(int rr=0;rr<2;rr++){
        #pragma unroll
        for(int reg=0;reg<4;reg++){
          int rowl = r0q + rr*16 + quad*4 + reg;
          stg[colc*72 + rowl] = f2bf(acc[rr][cc][reg]);
        }
      }
    }
    __syncthreads();
    int jbase = (nc-2)*128;
    for(int th=t; th<1024; th+=256){
      int row=th>>3, seg=th&7;
      int jg = jbase + row; int n = jg>>6, j = jg&63;
      *(uint4*)&Vt[(((size_t)(b*4+n)*64) + j)*512 + l0 + seg*8]
        = *(const uint4*)&stg[row*72 + seg*8];
    }
  } else {
    #pragma unroll
    for(int cc=0;cc<4;cc++){
      int colc = c0q + cc*16 + mrow;
      #pragma unroll
      for(int rr=0;rr<2;rr++){
        #pragma unroll
        for(int reg=0;reg<4;reg++){
          int rowl = r0q + rr*16 + quad*4 + reg;
          stg[rowl*136 + colc] = f2bf(acc[rr][cc][reg]);
        }
      }
    }
    __syncthreads();
    int gc0 = (nc-4)*128;
    for(int th=t; th<1024; th+=256){
      int row=th>>4, seg=th&15;
      *(uint4*)&G[((size_t)(tok0+row))*256 + gc0 + seg*8]
        = *(const uint4*)&stg[row*136 + seg*8];
    }
  }
}

// ---------------- qkvg v3 (layer 0 only): async swizzled weight staging ----------------
__global__ __launch_bounds__(256) void qkvg_kernel(
    const u16* __restrict__ A, const u16* __restrict__ Wt,
    u16* __restrict__ Q, u16* __restrict__ K,
    u16* __restrict__ Vt, u16* __restrict__ G)
{
  __shared__ u16 sW[128*128];      // 32 KB swizzled weights; reused as epilogue staging
  u16* stg = sW;
  int t = threadIdx.x, lane = t&63, wid = t>>6;
  int mrow = lane&15, quad = lane>>4;
  int srow = lane>>4, phys16l = lane&15;
  int r0q = (wid>>1)*32, c0q = (wid&1)*64;
  int tok0 = blockIdx.x*64;
  int b = tok0>>9, l0 = tok0&511;

  bf16x8 a0f[4], a1f[4];
  #pragma unroll
  for(int ks=0; ks<4; ks++){
    a0f[ks] = *(const bf16x8*)&A[(size_t)(tok0+r0q+mrow)*128 + ks*32+quad*8];
    a1f[ks] = *(const bf16x8*)&A[(size_t)(tok0+r0q+16+mrow)*128 + ks*32+quad*8];
  }

  for(int ch=0; ch<3; ch++){
    int nc = blockIdx.y*3 + ch;   // 0..5
    if(ch) __syncthreads();
    STAGE_TILE(sW, Wt + (size_t)nc*16384, 128, 0, wid, srow, phys16l);
    __syncthreads();

    f32x4 acc[2][4];
    #pragma unroll
    for(int rr=0;rr<2;rr++)
      #pragma unroll
      for(int cc=0;cc<4;cc++) acc[rr][cc] = (f32x4){0.f,0.f,0.f,0.f};
    #pragma unroll
    for(int ks=0; ks<4; ks++){
      #pragma unroll
      for(int cc=0; cc<4; cc++){
        bf16x8 bb = *(const bf16x8*)&sW[(c0q+cc*16+mrow)*128 + (((ks*4+quad)^mrow)<<3)];
        acc[0][cc] = __builtin_amdgcn_mfma_f32_16x16x32_bf16(a0f[ks],bb,acc[0][cc],0,0,0);
        acc[1][cc] = __builtin_amdgcn_mfma_f32_16x16x32_bf16(a1f[ks],bb,acc[1][cc],0,0,0);
      }
    }
    __syncthreads();
    qkvg_epilogue(nc, acc, stg, t, mrow, quad, r0q, c0q, b, l0, tok0, Q, K, Vt, G);
  }
}

// ---------------- fused MLP + qkvg(next layer): xn never touches HBM ----------------
__global__ __launch_bounds__(256) void mlpq_kernel(
    const u16* __restrict__ Gated, const u16* __restrict__ Wo,
    const u16* __restrict__ W1t, const float* __restrict__ b1,
    const u16* __restrict__ W2t, const float* __restrict__ b2,
    const float* __restrict__ Xin,
    const float* __restrict__ ln2w, const float* __restrict__ ln2b,
    const float* __restrict__ ln1w, const float* __restrict__ ln1b,
    float* __restrict__ Xout,
    const u16* __restrict__ Wq,   // next layer qkvg weights (nullptr on last layer)
    u16* __restrict__ Q, u16* __restrict__ K,
    u16* __restrict__ Vt, u16* __restrict__ G)
{
  __shared__ u16 sW[128*128];   // 32768 B: swizzled weights / fp32 X staging / qkvg epilogue stg
  __shared__ u16 sT[64*136];    // 17408 B: Z / H / xn (kept in LDS)
  int t=threadIdx.x, lane=t&63, wid=t>>6, mrow=lane&15, quad=lane>>4, r0=wid*16;
  int tok0=blockIdx.x*64;
  int srow = lane>>4, phys16l = lane&15;

  // gfrag direct from global (own rows)
  bf16x8 gfrag[8];
  #pragma unroll
  for(int ks=0;ks<8;ks++)
    gfrag[ks]=*(const bf16x8*)&Gated[(size_t)(tok0+r0+mrow)*256 + ks*32+quad*8];

  // ---- wo: K=256 in 2 halves (full N=128 resident)
  f32x4 yac[8];
  #pragma unroll
  for(int ch=0;ch<8;ch++) yac[ch]=(f32x4){0.f,0.f,0.f,0.f};
  STAGE_TILE(sW, Wo, 256, 0, wid, srow, phys16l);
  __syncthreads();
  #pragma unroll
  for(int kh=0; kh<2; kh++){
    #pragma unroll
    for(int ch=0;ch<8;ch++){
      #pragma unroll
      for(int ks=0;ks<4;ks++){
        bf16x8 b=*(const bf16x8*)&sW[(ch*16+mrow)*128 + (((ks*4+quad)^mrow)<<3)];
        yac[ch]=__builtin_amdgcn_mfma_f32_16x16x32_bf16(gfrag[kh*4+ks],b,yac[ch],0,0,0);
      }
    }
    if(kh==0){
      __syncthreads();
      STAGE_TILE(sW, Wo, 256, 128, wid, srow, phys16l);
      __syncthreads();
    }
  }

  // ---- Y = yac + Xin (regs); LN2 -> Z bf16 into sT (own rows)
  float yv[8][4];
  #pragma unroll
  for(int reg=0;reg<4;reg++){
    int rowl=r0+quad*4+reg, rowg=tok0+rowl;
    float s=0.f, sq=0.f;
    #pragma unroll
    for(int ch=0;ch<8;ch++){
      float v=yac[ch][reg]+Xin[(size_t)rowg*128+ch*16+mrow];
      yv[ch][reg]=v; s+=v; sq+=v*v;
    }
    #pragma unroll
    for(int m=1;m<16;m<<=1){ s+=__shfl_xor(s,m); sq+=__shfl_xor(sq,m); }
    float mu=s*(1.f/128.f);
    float var=sq*(1.f/128.f)-mu*mu;
    float rstd=rsqrtf(var+1e-5f);
    #pragma unroll
    for(int ch=0;ch<8;ch++){
      int col=ch*16+mrow;
      sT[rowl*136+col]=f2bf((yv[ch][reg]-mu)*rstd*ln2w[col]+ln2b[col]);
    }
  }
  bf16x8 az[4];
  #pragma unroll
  for(int ks=0;ks<4;ks++) az[ks]=*(const bf16x8*)&sT[(r0+mrow)*136+ks*32+quad*8];
  __syncthreads();

  // ---- ffn1: N=256 in 2 halves of 128 cols (full K=128 resident); H-half -> sT
  bf16x8 hfrag[8];
  #pragma unroll
  for(int nh=0; nh<2; nh++){
    STAGE_TILE(sW, W1t + (size_t)nh*16384, 128, 0, wid, srow, phys16l);
    __syncthreads();
    f32x4 hac[8];
    #pragma unroll
    for(int ch=0;ch<8;ch++) hac[ch]=(f32x4){0.f,0.f,0.f,0.f};
    #pragma unroll
    for(int ch=0;ch<8;ch++){
      #pragma unroll
      for(int ks=0;ks<4;ks++){
        bf16x8 b=*(const bf16x8*)&sW[(ch*16+mrow)*128 + (((ks*4+quad)^mrow)<<3)];
        hac[ch]=__builtin_amdgcn_mfma_f32_16x16x32_bf16(az[ks],b,hac[ch],0,0,0);
      }
    }
    #pragma unroll
    for(int ch=0;ch<8;ch++){
      float bs=b1[nh*128+ch*16+mrow];
      #pragma unroll
      for(int reg=0;reg<4;reg++)
        sT[(r0+quad*4+reg)*136 + ch*16+mrow]=f2bf(gelu_f(hac[ch][reg]+bs));
    }
    #pragma unroll
    for(int ks=0;ks<4;ks++) hfrag[nh*4+ks]=*(const bf16x8*)&sT[(r0+mrow)*136+ks*32+quad*8];
    __syncthreads();
  }

  // ---- ffn2: K=256 in 2 halves (full N=128 resident)
  f32x4 xac[8];
  #pragma unroll
  for(int ch=0;ch<8;ch++) xac[ch]=(f32x4){0.f,0.f,0.f,0.f};
  STAGE_TILE(sW, W2t, 256, 0, wid, srow, phys16l);
  __syncthreads();
  #pragma unroll
  for(int kh=0; kh<2; kh++){
    #pragma unroll
    for(int ch=0;ch<8;ch++){
      #pragma unroll
      for(int ks=0;ks<4;ks++){
        bf16x8 b=*(const bf16x8*)&sW[(ch*16+mrow)*128 + (((ks*4+quad)^mrow)<<3)];
        xac[ch]=__builtin_amdgcn_mfma_f32_16x16x32_bf16(hfrag[kh*4+ks],b,xac[ch],0,0,0);
      }
    }
    __syncthreads();
    if(kh==0){
      STAGE_TILE(sW, W2t, 256, 128, wid, srow, phys16l);
      __syncthreads();
    }
  }

  // ---- epilogue: X = xac + b2 + Y; LN1(next) -> sT (xn, LDS-resident)
  float* fst = (float*)sW;       // [64][128] = 32768 B
  #pragma unroll
  for(int reg=0;reg<4;reg++){
    int rowl=r0+quad*4+reg;
    float xv[8], s=0.f, sq=0.f;
    #pragma unroll
    for(int ch=0;ch<8;ch++){
      float v=xac[ch][reg]+b2[ch*16+mrow]+yv[ch][reg];
      xv[ch]=v; s+=v; sq+=v*v;
    }
    #pragma unroll
    for(int m=1;m<16;m<<=1){ s+=__shfl_xor(s,m); sq+=__shfl_xor(sq,m); }
    float mu=s*(1.f/128.f);
    float var=sq*(1.f/128.f)-mu*mu;
    float rstd=rsqrtf(var+1e-5f);
    #pragma unroll
    for(int ch=0;ch<8;ch++){
      int col=ch*16+mrow;
      fst[rowl*128+col]=xv[ch];
      sT[rowl*136+col]=f2bf((xv[ch]-mu)*rstd*ln1w[col]+ln1b[col]);
    }
  }
  __syncthreads();
  for(int th=t; th<2048; th+=256){
    int row=th>>5, c4=(th&31)*4;
    *(float4*)&Xout[(size_t)(tok0+row)*128+c4]=*(const float4*)&fst[row*128+c4];
  }

  if(!Wq) return;

  // ---- fused qkvg for next layer: A-frags from sT (xn in LDS)
  int r0q = (wid>>1)*32, c0q = (wid&1)*64;
  int b = tok0>>9, l0 = tok0&511;
  bf16x8 a0f[4], a1f[4];
  #pragma unroll
  for(int ks=0; ks<4; ks++){
    a0f[ks] = *(const bf16x8*)&sT[(r0q+mrow)*136 + ks*32+quad*8];
    a1f[ks] = *(const bf16x8*)&sT[(r0q+16+mrow)*136 + ks*32+quad*8];
  }
  __syncthreads();   // Xout reads of fst(sW) done before STAGE overwrites

  for(int nc=0; nc<6; nc++){
    if(nc) __syncthreads();   // prev epilogue's stg reads done
    STAGE_TILE(sW, Wq + (size_t)nc*16384, 128, 0, wid, srow, phys16l);
    __syncthreads();

    f32x4 acc[2][4];
    #pragma unroll
    for(int rr=0;rr<2;rr++)
      #pragma unroll
      for(int cc=0;cc<4;cc++) acc[rr][cc] = (f32x4){0.f,0.f,0.f,0.f};
    #pragma unroll
    for(int ks=0; ks<4; ks++){
      #pragma unroll
      for(int cc=0; cc<4; cc++){
        bf16x8 bb = *(const bf16x8*)&sW[(c0q+cc*16+mrow)*128 + (((ks*4+quad)^mrow)<<3)];
        acc[0][cc] = __builtin_amdgcn_mfma_f32_16x16x32_bf16(a0f[ks],bb,acc[0][cc],0,0,0);
        acc[1][cc] = __builtin_amdgcn_mfma_f32_16x16x32_bf16(a1f[ks],bb,acc[1][cc],0,0,0);
      }
    }
    __syncthreads();
    qkvg_epilogue(nc, acc, sW, t, mrow, quad, r0q, c0q, b, l0, tok0, Q, K, Vt, G);
  }
}

// ---------------- retention v4: single-buffered (23.6 KB LDS, 6 blocks/CU) + fused GN/gate ----------------
__global__ __launch_bounds__(256) void retmfma_kernel(
    const u16* __restrict__ Q, const u16* __restrict__ K,
    const u16* __restrict__ Vt, const u16* __restrict__ G,
    const float* __restrict__ gnw, const float* __restrict__ gnb,
    u16* __restrict__ Gated, float4 log2g)
{
  int idx = blockIdx.x;
  int bn = ((idx>>6)<<3) | (idx&7);
  int lt = (idx>>3)&7;
  int n = bn & 3, b = bn >> 2;
  float lg2g = (n==0)?log2g.x:(n==1)?log2g.y:(n==2)?log2g.z:log2g.w;
  __shared__ u16 sK[64][40];
  __shared__ u16 sVt[64][72];
  __shared__ u16 sS[64][72];
  int t = threadIdx.x, lane = t&63, wid = t>>6;
  int mrow = lane&15, quad = lane>>4;
  int r0 = wid*16;

  // qa direct from global (own rows)
  bf16x8 qa = *(const bf16x8*)&Q[((size_t)bn*512 + lt*64 + r0+mrow)*32 + quad*8];

  f32x4 oacc[4];
  #pragma unroll
  for(int cc=0;cc<4;cc++) oacc[cc] = (f32x4){0.f,0.f,0.f,0.f};
  float gp1 = exp2f(lg2g), gp2 = gp1*gp1, gp3 = gp2*gp1;
  float gpow[4] = {1.f, gp1, gp2, gp3};
  float gw[4], gb[4];
  #pragma unroll
  for(int cc=0;cc<4;cc++){ gw[cc]=gnw[n*64+cc*16+mrow]; gb[cc]=gnb[n*64+cc*16+mrow]; }
  int rowl0 = lt*64 + r0 + quad*4;

  for(int mt=0; mt<=lt; mt++){
    if(mt) __syncthreads();
    {
      int row = t>>2, c8 = (t&3)*8;
      *(uint4*)&sK[row][c8] = *(const uint4*)&K[((size_t)bn*512 + mt*64 + row)*32 + c8];
      int vrow = t>>3, vc8 = (t&7)*8;
      *(uint4*)&sVt[vrow][vc8]    = *(const uint4*)&Vt[((size_t)bn*64 + vrow)*512    + mt*64 + vc8];
      *(uint4*)&sVt[vrow+32][vc8] = *(const uint4*)&Vt[((size_t)bn*64 + vrow+32)*512 + mt*64 + vc8];
    }
    __syncthreads();
    f32x4 sacc[4];
    #pragma unroll
    for(int cc=0;cc<4;cc++){
      bf16x8 bb = *(const bf16x8*)&sK[cc*16+mrow][quad*8];
      sacc[cc] = __builtin_amdgcn_mfma_f32_16x16x32_bf16(qa,bb,(f32x4){0.f,0.f,0.f,0.f},0,0,0);
    }
    #pragma unroll
    for(int cc=0;cc<4;cc++){
      int colm = mt*64 + cc*16 + mrow;
      int d0 = rowl0 - colm;
      float w0 = exp2f(lg2g*(float)d0);
      #pragma unroll
      for(int reg=0;reg<4;reg++){
        float w = (d0+reg>=0) ? w0*gpow[reg] : 0.f;
        sS[r0+quad*4+reg][cc*16+mrow] = f2bf(sacc[cc][reg]*w);
      }
    }
    __syncthreads();
    #pragma unroll
    for(int ks=0;ks<2;ks++){
      bf16x8 a = *(const bf16x8*)&sS[r0+mrow][ks*32+quad*8];
      #pragma unroll
      for(int cc=0;cc<4;cc++){
        bf16x8 bb = *(const bf16x8*)&sVt[cc*16+mrow][ks*32+quad*8];
        oacc[cc] = __builtin_amdgcn_mfma_f32_16x16x32_bf16(a,bb,oacc[cc],0,0,0);
      }
    }
  }

  __syncthreads();
  #pragma unroll
  for(int reg=0;reg<4;reg++){
    float s=0.f, sq=0.f;
    #pragma unroll
    for(int cc=0;cc<4;cc++){ float v=oacc[cc][reg]; s+=v; sq+=v*v; }
    #pragma unroll
    for(int m=1;m<16;m<<=1){ s+=__shfl_xor(s,m); sq+=__shfl_xor(sq,m); }
    float mu = s*(1.f/64.f);
    float var = sq*(1.f/64.f) - mu*mu;
    float rn = rsqrtf(var + 1e-5f);
    int rowl = r0 + quad*4 + reg;
    int l = lt*64 + rowl;
    size_t gbase = ((size_t)(b*512 + l))*256 + n*64;
    #pragma unroll
    for(int cc=0;cc<4;cc++){
      float gg = bf2f(G[gbase + cc*16+mrow]);
      float gate = gg/(1.f+expf(-gg));
      sS[rowl][cc*16+mrow] = f2bf(gate*((oacc[cc][reg]-mu)*rn*gw[cc] + gb[cc]));
    }
  }
  __syncthreads();
  for(int th=t; th<512; th+=256){
    int row=th>>3, seg=th&7;
    *(uint4*)&Gated[((size_t)(b*512 + lt*64 + row))*256 + n*64 + seg*8]
      = *(const uint4*)&sS[row][seg*8];
  }
}

// ---------------- decoder (MFMA): softmax(gelu(X@w1+b1)@w2+b2) ----------------
__global__ __launch_bounds__(256) void dec_kernel(
    const float* __restrict__ X, const u16* __restrict__ W1t,
    const float* __restrict__ b1, const float* __restrict__ w2,
    const float* __restrict__ b2, float* __restrict__ out)
{
  __shared__ u16 sA[64][136];
  __shared__ u16 sW[64][136];
  __shared__ float sH[64][68];
  __shared__ float sL[64*20];
  __shared__ float sw2[64*20];
  __shared__ float sb2[20];
  int t = threadIdx.x, lane = t&63, wid = t>>6;
  int mrow = lane&15, quad = lane>>4;
  int tok0 = blockIdx.x*64;

  for(int th=t; th<2048; th+=256){
    int row=th>>5, c4=(th&31)*4;
    float4 v = *(const float4*)&X[(size_t)(tok0+row)*128 + c4];
    ushort4 p; p.x=f2bf(v.x); p.y=f2bf(v.y); p.z=f2bf(v.z); p.w=f2bf(v.w);
    *(ushort4*)&sA[row][c4] = p;
  }
  for(int th=t; th<1024; th+=256){
    int row=th>>4, c8=(th&15)*8;
    *(uint4*)&sW[row][c8] = *(const uint4*)&W1t[(size_t)row*128 + c8];
  }
  for(int i=t;i<1280;i+=256) sw2[i]=w2[i];
  if(t<20) sb2[t]=b2[t];
  __syncthreads();

  int r0 = wid*16;
  f32x4 acc[4];
  #pragma unroll
  for(int cc=0;cc<4;cc++) acc[cc] = (f32x4){0.f,0.f,0.f,0.f};
  #pragma unroll
  for(int ks=0; ks<4; ks++){
    int koff = ks*32 + quad*8;
    bf16x8 a = *(const bf16x8*)&sA[r0+mrow][koff];
    #pragma unroll
    for(int cc=0; cc<4; cc++){
      bf16x8 b = *(const bf16x8*)&sW[cc*16+mrow][koff];
      acc[cc] = __builtin_amdgcn_mfma_f32_16x16x32_bf16(a,b,acc[cc],0,0,0);
    }
  }
  #pragma unroll
  for(int cc=0;cc<4;cc++){
    int col = cc*16 + mrow;
    float bb = b1[col];
    #pragma unroll
    for(int reg=0;reg<4;reg++){
      sH[r0 + quad*4 + reg][col] = gelu_f(acc[cc][reg] + bb);
    }
  }
  __syncthreads();

  for(int task=t; task<1280; task+=256){
    int tk = task/20, o = task - tk*20;
    float a = sb2[o];
    for(int k=0;k<64;k++) a += sH[tk][k]*sw2[k*20+o];
    sL[tk*20+o] = a;
  }
  __syncthreads();
  if(t < 64){
    float mx = -1e30f;
    #pragma unroll
    for(int o=0;o<20;o++) mx = fmaxf(mx, sL[t*20+o]);
    float sum = 0.f;
    float e[20];
    #pragma unroll
    for(int o=0;o<20;o++){ e[o]=expf(sL[t*20+o]-mx); sum += e[o]; }
    float inv = 1.f/sum;
    #pragma unroll
    for(int o=0;o<20;o++) sL[t*20+o] = e[o]*inv;
  }
  __syncthreads();
  for(int th=t; th<1280; th+=256){
    out[(size_t)tok0*20 + th] = sL[th];
  }
}

extern "C" void kernel_launch(void* const* d_in, const int* in_sizes, int n_in,
                              void* d_out, int out_size, void* d_ws, size_t ws_size,
                              hipStream_t stream) {
  (void)in_sizes; (void)n_in; (void)out_size; (void)ws_size;
  const float* x      = (const float*)d_in[0];
  const float* rem_w1 = (const float*)d_in[1];
  const float* rem_b1 = (const float*)d_in[2];
  const float* rem_w2 = (const float*)d_in[3];
  const float* rem_b2 = (const float*)d_in[4];
  const float* rem_w3 = (const float*)d_in[5];
  const float* rem_b3 = (const float*)d_in[6];
  const float* wq     = (const float*)d_in[7];
  const float* wk     = (const float*)d_in[8];
  const float* wv     = (const float*)d_in[9];
  const float* wg     = (const float*)d_in[10];
  const float* wo     = (const float*)d_in[11];
  const float* gn_w   = (const float*)d_in[12];
  const float* gn_b   = (const float*)d_in[13];
  const float* ln1_w  = (const float*)d_in[14];
  const float* ln1_b  = (const float*)d_in[15];
  const float* ln2_w  = (const float*)d_in[16];
  const float* ln2_b  = (const float*)d_in[17];
  const float* ffn_w1 = (const float*)d_in[18];
  const float* ffn_b1 = (const float*)d_in[19];
  const float* ffn_w2 = (const float*)d_in[20];
  const float* ffn_b2 = (const float*)d_in[21];
  const float* dec_w1 = (const float*)d_in[22];
  const float* dec_b1 = (const float*)d_in[23];
  const float* dec_w2 = (const float*)d_in[24];
  const float* dec_b2 = (const float*)d_in[25];
  float* outp = (float*)d_out;

  const size_t S128 = (size_t)BT*128;
  const size_t S256 = (size_t)BT*256;
  float* ws = (float*)d_ws;
  float* Xb = ws;                  // residual X        (S128 f32)
  u16*  Qb16    = (u16*)(Xb + S128);     // Q bf16 head-layout (BT*32)
  u16*  Kb16    = Qb16 + (size_t)BT*32;
  u16*  Vt16    = Kb16 + (size_t)BT*32;  // V bf16 transposed (BT*64)
  u16*  XnBf    = Vt16 + (size_t)BT*64;  // LN out bf16 (layer-0 only)
  u16*  GBf     = XnBf + S128;           // G bf16        (S256)
  u16*  GatedBf = GBf + S256;            // gated        (S256)
  u16*  WtBf    = GatedBf + S256;        // bf16 weights  (804864 u16)

  double lgA = log(1.0/32.0), lgB = log(1.0/512.0);
  float4 l2g;
  {
    double g0 = 1.0 - exp(lgA + 0.0*(lgB-lgA)/3.0);
    double g1 = 1.0 - exp(lgA + 1.0*(lgB-lgA)/3.0);
    double g2 = 1.0 - exp(lgA + 2.0*(lgB-lgA)/3.0);
    double g3 = 1.0 - exp(lgA + 3.0*(lgB-lgA)/3.0);
    l2g.x = (float)(log(g0)/log(2.0));
    l2g.y = (float)(log(g1)/log(2.0));
    l2g.z = (float)(log(g2)/log(2.0));
    l2g.w = (float)(log(g3)/log(2.0));
  }

  wconv_kernel<<<3144, 256, 0, stream>>>(wq, wk, wv, wg, wo, ffn_w1, ffn_w2, dec_w1,
                                         rem_w2, rem_w3, WtBf);
  embed_kernel<<<BT/64, 256, 0, stream>>>(x, rem_w1, rem_b1, rem_b2, rem_b3,
                                          WtBf+794624, ln1_w, ln1_b, Xb, XnBf);
  qkvg_kernel<<<dim3(BT/64,2), 256, 0, stream>>>(XnBf, WtBf, Qb16, Kb16, Vt16, GBf);

  for(int li=0; li<4; li++){
    u16* Wt_l = WtBf + (size_t)li*196608;
    const float* gnw_l = gn_w + (size_t)li*VDIM;
    const float* gnb_l = gn_b + (size_t)li*VDIM;
    const float* l2w = ln2_w + (size_t)li*HID, *l2b = ln2_b + (size_t)li*HID;
    const float* f1b = ffn_b1 + (size_t)li*FFND;
    const float* f2b = ffn_b2 + (size_t)li*HID;
    int nli = (li+1)&3;
    const float* n1w = ln1_w + (size_t)nli*HID, *n1b = ln1_b + (size_t)nli*HID;
    const u16* Wq_next = (li<3) ? (WtBf + (size_t)(li+1)*196608) : nullptr;

    retmfma_kernel<<<2048, 256, 0, stream>>>(Qb16, Kb16, Vt16, GBf, gnw_l, gnb_l, GatedBf, l2g);
    mlpq_kernel<<<BT/64, 256, 0, stream>>>(
        GatedBf, Wt_l+98304, Wt_l+131072, f1b, Wt_l+163840, f2b,
        Xb, l2w, l2b, n1w, n1b, Xb,
        Wq_next, Qb16, Kb16, Vt16, GBf);
  }

  dec_kernel<<<BT/64, 256, 0, stream>>>(Xb, WtBf+786432, dec_b1, dec_w2, dec_b2, outp);
}